// Round 10
// baseline (384.692 us; speedup 1.0000x reference)
//
#include <hip/hip_runtime.h>
#include <hip/hip_cooperative_groups.h>
#include <hip/hip_bf16.h>
#include <hip/hip_fp16.h>
#include <float.h>

#define F 128          // hidden = H*C
#define HEADS 4
#define CPH 32

using f16x8 = __attribute__((ext_vector_type(8))) _Float16;
using f32x4 = __attribute__((ext_vector_type(4))) float;

namespace cg = cooperative_groups;

// ---------------- fused preprocessing (cooperative) ----------------
// One kernel: convw (W->W^T fp16) || zero deg -> count deg -> hierarchical
// exclusive scan -> row_ptr/cursor -> scatter srcs. 256 blocks x 1024 thr
// (1 block/CU, co-resident). Replaces 7 dispatches + 1 memset.

__global__ __launch_bounds__(1024) void prep_kernel(
    const int* __restrict__ src, const int* __restrict__ dst,
    const float* __restrict__ W0, const float* __restrict__ W1,
    const float* __restrict__ W2, const float* __restrict__ W3,
    _Float16* __restrict__ T0, _Float16* __restrict__ T1,
    _Float16* __restrict__ T2, _Float16* __restrict__ T3,
    int* __restrict__ deg, int* __restrict__ excl, int* __restrict__ bsums,
    int* __restrict__ row_ptr, int* __restrict__ cursor, int* __restrict__ srcs,
    int N, int E)
{
    cg::grid_group grid = cg::this_grid();
    __shared__ int tmp[1024];
    const int gid = blockIdx.x * 1024 + threadIdx.x;
    const int gstride = gridDim.x * 1024;

    // P0: weight transpose+convert (independent) and zero deg
    for (int i = gid; i < 4 * F * F; i += gstride) {
        int m = i >> 14, tid = i & 16383;          // tid = n*128+k
        int n = tid >> 7, k = tid & 127;
        const float* W = m == 0 ? W0 : m == 1 ? W1 : m == 2 ? W2 : W3;
        _Float16*    T = m == 0 ? T0 : m == 1 ? T1 : m == 2 ? T2 : T3;
        T[tid] = (_Float16)W[k * F + n];
    }
    for (int i = gid; i < N; i += gstride) deg[i] = 0;
    grid.sync();

    // P1: degree count
    for (int i = gid; i < E; i += gstride) atomicAdd(&deg[dst[i]], 1);
    grid.sync();

    // P2: per-chunk scan (chunk = 1024), blocks 0..nchunks-1
    const int nchunks = (N + 1023) / 1024;
    if (blockIdx.x < nchunks) {
        int i = blockIdx.x * 1024 + threadIdx.x;
        int v = (i < N) ? deg[i] : 0;
        tmp[threadIdx.x] = v;
        __syncthreads();
        for (int o = 1; o < 1024; o <<= 1) {
            int a = (threadIdx.x >= o) ? tmp[threadIdx.x - o] : 0;
            __syncthreads();
            tmp[threadIdx.x] += a;
            __syncthreads();
        }
        if (i < N) excl[i] = tmp[threadIdx.x] - v;
        if (threadIdx.x == 1023) bsums[blockIdx.x] = tmp[1023];
    }
    grid.sync();

    // P3: block 0 scans chunk sums (nchunks <= 1024)
    if (blockIdx.x == 0) {
        int v = (threadIdx.x < nchunks) ? bsums[threadIdx.x] : 0;
        tmp[threadIdx.x] = v;
        __syncthreads();
        for (int o = 1; o < 1024; o <<= 1) {
            int a = (threadIdx.x >= o) ? tmp[threadIdx.x - o] : 0;
            __syncthreads();
            tmp[threadIdx.x] += a;
            __syncthreads();
        }
        if (threadIdx.x < nchunks) bsums[threadIdx.x] = tmp[threadIdx.x] - v;
    }
    grid.sync();

    // P4: row_ptr + cursor
    for (int i = gid; i < N; i += gstride) {
        int v = excl[i] + bsums[i >> 10];
        row_ptr[i] = v;
        cursor[i] = v;
    }
    if (gid == 0) row_ptr[N] = E;
    grid.sync();

    // P5: scatter src ids into dst-sorted order
    for (int i = gid; i < E; i += gstride) {
        int pos = atomicAdd(&cursor[dst[i]], 1);
        srcs[pos] = src[i];
    }
}

// ---------------- MFMA GEMM, LDS-staged B ----------------
// grid (nb, 2): blockIdx.y = matrix (0: Wl -> xl fp16, 1: Wr -> xr fp32).
// 256 thr = 4 waves x 16 rows = 64 rows/block. W^T staged in LDS with +1-granule
// row padding (17 granules/row -> 2-way bank conflict = free). B frags via
// ds_read_b128 (~12cyc) instead of per-iter L2 (~200cyc, the R8 mistake) and
// without the 128-VGPR B-residency that capped R9 at 8 waves/CU.
// VGPR ~70, LDS 34.8KB -> 4 blocks/CU, 16 waves/CU.
// A/B share the k-slot map (k = t*32+g*8+j); C/D: col=lane&15, row=(lane>>4)*4+reg.

template<int A_FP32>
__global__ __launch_bounds__(256) void mfma_gemm_kernel(
    const void* __restrict__ Xin,
    const _Float16* __restrict__ Wlt, const float* __restrict__ bl,
    const _Float16* __restrict__ Wrt, const float* __restrict__ br,
    _Float16* __restrict__ xl, float* __restrict__ xr, int N)
{
    const int m = blockIdx.y;
    const _Float16* Wt = m ? Wrt : Wlt;

    __shared__ f16x8 Ws[F * 17];             // 128 rows x 17 granules (16 data + 1 pad)
    for (int i = threadIdx.x; i < F * 16; i += 256) {
        int row = i >> 4, g = i & 15;
        Ws[row * 17 + g] = ((const f16x8*)Wt)[i];
    }
    __syncthreads();

    const int wid  = threadIdx.x >> 6;
    const int lane = threadIdx.x & 63;
    const int row0 = blockIdx.x * 64 + wid * 16;
    const int arow = lane & 15;
    const int g    = lane >> 4;              // 0..3

    // A fragments (inline fp32->fp16 convert for layer 1)
    int xrow = row0 + arow;
    if (xrow >= N) xrow = N - 1;             // clamp (C stores guarded)
    f16x8 af[4];
    if (A_FP32) {
        const float* xp = (const float*)Xin + (size_t)xrow * F + g * 8;
        #pragma unroll
        for (int t = 0; t < 4; ++t) {
            float4 lo = *(const float4*)(xp + t * 32);
            float4 hi = *(const float4*)(xp + t * 32 + 4);
            f16x8 a;
            a[0] = (_Float16)lo.x; a[1] = (_Float16)lo.y; a[2] = (_Float16)lo.z; a[3] = (_Float16)lo.w;
            a[4] = (_Float16)hi.x; a[5] = (_Float16)hi.y; a[6] = (_Float16)hi.z; a[7] = (_Float16)hi.w;
            af[t] = a;
        }
    } else {
        const _Float16* xp = (const _Float16*)Xin + (size_t)xrow * F + g * 8;
        #pragma unroll
        for (int t = 0; t < 4; ++t)
            af[t] = *(const f16x8*)(xp + t * 32);
    }

    f32x4 acc[8];
    #pragma unroll
    for (int nt = 0; nt < 8; ++nt) acc[nt] = (f32x4){0.f, 0.f, 0.f, 0.f};

    #pragma unroll
    for (int t = 0; t < 4; ++t)
        #pragma unroll
        for (int nt = 0; nt < 8; ++nt) {
            f16x8 b = Ws[(nt * 16 + arow) * 17 + (t * 4 + g)];
            acc[nt] = __builtin_amdgcn_mfma_f32_16x16x32_f16(af[t], b, acc[nt], 0, 0, 0);
        }

    const float* bias = m ? br : bl;
    #pragma unroll
    for (int nt = 0; nt < 8; ++nt) {
        int ccol = nt * 16 + (lane & 15);
        float bv = bias[ccol];
        #pragma unroll
        for (int r2 = 0; r2 < 4; ++r2) {
            int crow = row0 + (lane >> 4) * 4 + r2;
            if (crow < N) {
                float v = acc[nt][r2] + bv;
                if (m == 0) xl[(size_t)crow * F + ccol] = (_Float16)v;
                else        xr[(size_t)crow * F + ccol] = v;
            }
        }
    }
}

// ---------------- fused edge phase (R7-proven, fp16 xl gather) ----------------
// 1 wave per node; thread t owns channels (2t, 2t+1); head group = 16 lanes.
// Plain exp (logits O(5), exp-safe in fp32). 4 independent chains in flight.
// out_half: layer-1 writes fp16 h (feeds layer-2 MFMA GEMM directly).

__device__ __forceinline__ float edge_logit(float2 v, float2 xr_t, float2 a_t) {
    float e0 = v.x + xr_t.x; e0 = e0 >= 0.f ? e0 : 0.2f * e0;
    float e1 = v.y + xr_t.y; e1 = e1 >= 0.f ? e1 : 0.2f * e1;
    float p = e0 * a_t.x + e1 * a_t.y;
    p += __shfl_xor(p, 8);
    p += __shfl_xor(p, 4);
    p += __shfl_xor(p, 2);
    p += __shfl_xor(p, 1);
    return p;
}

__global__ __launch_bounds__(256) void gat_edge_kernel(
    const __half2* __restrict__ xlh, const float2* __restrict__ xr2,
    const int* __restrict__ srcs, const int* __restrict__ row_ptr,
    const float2* __restrict__ att2, const float2* __restrict__ bias2,
    float2* __restrict__ outf, __half2* __restrict__ outh,
    int N, int do_relu, int out_half)
{
    int node = blockIdx.x * 4 + threadIdx.y;
    int t = threadIdx.x;                       // 0..63
    if (node >= N) return;
    float2 xr_t = xr2[(size_t)node * 64 + t];
    float2 a_t  = att2[t];
    int beg = row_ptr[node], end = row_ptr[node + 1];
    float s = 0.f;
    float ox = 0.f, oy = 0.f;
    int i = beg;
    for (; i + 4 <= end; i += 4) {
        int sn0 = srcs[i], sn1 = srcs[i + 1], sn2 = srcs[i + 2], sn3 = srcs[i + 3];
        float2 v0 = __half22float2(xlh[(size_t)sn0 * 64 + t]);
        float2 v1 = __half22float2(xlh[(size_t)sn1 * 64 + t]);
        float2 v2 = __half22float2(xlh[(size_t)sn2 * 64 + t]);
        float2 v3 = __half22float2(xlh[(size_t)sn3 * 64 + t]);
        float p0 = edge_logit(v0, xr_t, a_t);
        float p1 = edge_logit(v1, xr_t, a_t);
        float p2 = edge_logit(v2, xr_t, a_t);
        float p3 = edge_logit(v3, xr_t, a_t);
        float w0 = __expf(p0), w1 = __expf(p1), w2 = __expf(p2), w3 = __expf(p3);
        s += (w0 + w1) + (w2 + w3);
        ox = fmaf(w0, v0.x, ox); oy = fmaf(w0, v0.y, oy);
        ox = fmaf(w1, v1.x, ox); oy = fmaf(w1, v1.y, oy);
        ox = fmaf(w2, v2.x, ox); oy = fmaf(w2, v2.y, oy);
        ox = fmaf(w3, v3.x, ox); oy = fmaf(w3, v3.y, oy);
    }
    for (; i < end; ++i) {
        int sn = srcs[i];
        float2 v = __half22float2(xlh[(size_t)sn * 64 + t]);
        float p = edge_logit(v, xr_t, a_t);
        float w = __expf(p);
        s += w;
        ox = fmaf(w, v.x, ox); oy = fmaf(w, v.y, oy);
    }
    float inv = 1.f / (s + 1e-16f);
    float2 bi = bias2[t];
    float rx = ox * inv + bi.x;
    float ry = oy * inv + bi.y;
    if (do_relu) { rx = fmaxf(rx, 0.f); ry = fmaxf(ry, 0.f); }
    if (out_half) {
        outh[(size_t)node * 64 + t] = __floats2half2_rn(rx, ry);
    } else {
        float2 rr; rr.x = rx; rr.y = ry;
        outf[(size_t)node * 64 + t] = rr;
    }
}

// ---------------- launch ----------------

extern "C" void kernel_launch(void* const* d_in, const int* in_sizes, int n_in,
                              void* d_out, int out_size, void* d_ws, size_t ws_size,
                              hipStream_t stream)
{
    const float* x    = (const float*)d_in[0];
    const int*   ei   = (const int*)d_in[1];
    const float* Wl1  = (const float*)d_in[2];
    const float* Wr1  = (const float*)d_in[3];
    const float* Wl2  = (const float*)d_in[4];
    const float* Wr2  = (const float*)d_in[5];
    const float* bl1  = (const float*)d_in[6];
    const float* br1  = (const float*)d_in[7];
    const float* bl2  = (const float*)d_in[8];
    const float* br2  = (const float*)d_in[9];
    const float* att1 = (const float*)d_in[10];
    const float* att2 = (const float*)d_in[11];
    const float* b1   = (const float*)d_in[12];
    const float* b2   = (const float*)d_in[13];

    const int N = in_sizes[0] / F;
    const int E = in_sizes[1] / 2;
    const int* src = ei;
    const int* dst = ei + E;

    char* ws = (char*)d_ws;
    size_t off = 0;
    auto alloc = [&](size_t bytes) -> void* {
        void* p = ws + off;
        off = (off + bytes + 255) & ~(size_t)255;
        return p;
    };
    _Float16* hh   = (_Float16*)alloc((size_t)N * F * sizeof(_Float16));  // fp16 h (layer2 in)
    _Float16* xlh  = (_Float16*)alloc((size_t)N * F * sizeof(_Float16));  // fp16 xl
    float*    xr   = (float*)alloc((size_t)N * F * sizeof(float));        // fp32 xr
    _Float16* Wt1l = (_Float16*)alloc((size_t)F * F * sizeof(_Float16));
    _Float16* Wt1r = (_Float16*)alloc((size_t)F * F * sizeof(_Float16));
    _Float16* Wt2l = (_Float16*)alloc((size_t)F * F * sizeof(_Float16));
    _Float16* Wt2r = (_Float16*)alloc((size_t)F * F * sizeof(_Float16));
    int* row_ptr   = (int*)alloc((size_t)(N + 1) * sizeof(int));
    int* deg       = (int*)alloc((size_t)N * sizeof(int));
    int* excl      = (int*)alloc((size_t)N * sizeof(int));
    int* bsums     = (int*)alloc((size_t)1024 * sizeof(int));
    int* cursor    = (int*)alloc((size_t)N * sizeof(int));
    int* srcs      = (int*)alloc((size_t)E * sizeof(int));

    // fused preprocessing: convw + CSR build, one cooperative dispatch
    {
        int n = N, e = E;
        void* args[] = {
            (void*)&src, (void*)&dst,
            (void*)&Wl1, (void*)&Wr1, (void*)&Wl2, (void*)&Wr2,
            (void*)&Wt1l, (void*)&Wt1r, (void*)&Wt2l, (void*)&Wt2r,
            (void*)&deg, (void*)&excl, (void*)&bsums,
            (void*)&row_ptr, (void*)&cursor, (void*)&srcs,
            (void*)&n, (void*)&e
        };
        hipLaunchCooperativeKernel((const void*)prep_kernel,
                                   dim3(256), dim3(1024), args, 0, stream);
    }

    const int gemm_blocks = (N + 63) / 64;
    dim3 gemm_grid(gemm_blocks, 2);
    dim3 eb(64, 4);
    const int edge_blocks = (N + 3) / 4;

    // layer 1 (A fp32, converted inline)
    mfma_gemm_kernel<1><<<gemm_grid, 256, 0, stream>>>(
        x, Wt1l, bl1, Wt1r, br1, xlh, xr, N);
    gat_edge_kernel<<<edge_blocks, eb, 0, stream>>>(
        (const __half2*)xlh, (const float2*)xr, srcs, row_ptr,
        (const float2*)att1, (const float2*)b1,
        nullptr, (__half2*)hh, N, 1, 1);

    // layer 2 (A fp16 from edge layer 1)
    mfma_gemm_kernel<0><<<gemm_grid, 256, 0, stream>>>(
        hh, Wt2l, bl2, Wt2r, br2, xlh, xr, N);
    gat_edge_kernel<<<edge_blocks, eb, 0, stream>>>(
        (const __half2*)xlh, (const float2*)xr, srcs, row_ptr,
        (const float2*)att2, (const float2*)b2,
        (float2*)d_out, nullptr, N, 0, 0);
}

// Round 11
// 238.641 us; speedup vs baseline: 1.6120x; 1.6120x over previous
//
#include <hip/hip_runtime.h>
#include <hip/hip_bf16.h>
#include <hip/hip_fp16.h>
#include <float.h>

#define F 128          // hidden = H*C
#define HEADS 4
#define CPH 32

using f16x8 = __attribute__((ext_vector_type(8))) _Float16;
using f32x4 = __attribute__((ext_vector_type(4))) float;

// ---------------- CSR build (R9-proven separate kernels; coop grid.sync was 221us) ----

__global__ void count_deg_kernel(const int* __restrict__ dst, int* __restrict__ deg, int E) {
    int i = blockIdx.x * blockDim.x + threadIdx.x;
    if (i < E) atomicAdd(&deg[dst[i]], 1);
}

__global__ __launch_bounds__(1024) void scan1_kernel(const int* __restrict__ deg,
                                                     int* __restrict__ excl,
                                                     int* __restrict__ bsums, int n) {
    __shared__ int tmp[1024];
    int i = blockIdx.x * 1024 + threadIdx.x;
    int v = (i < n) ? deg[i] : 0;
    tmp[threadIdx.x] = v;
    __syncthreads();
    for (int o = 1; o < 1024; o <<= 1) {
        int a = (threadIdx.x >= o) ? tmp[threadIdx.x - o] : 0;
        __syncthreads();
        tmp[threadIdx.x] += a;
        __syncthreads();
    }
    if (i < n) excl[i] = tmp[threadIdx.x] - v;
    if (threadIdx.x == 1023) bsums[blockIdx.x] = tmp[1023];
}

__global__ __launch_bounds__(1024) void scan2_kernel(int* __restrict__ bsums, int nb) {
    __shared__ int tmp[1024];
    int v = (threadIdx.x < nb) ? bsums[threadIdx.x] : 0;
    tmp[threadIdx.x] = v;
    __syncthreads();
    for (int o = 1; o < 1024; o <<= 1) {
        int a = (threadIdx.x >= o) ? tmp[threadIdx.x - o] : 0;
        __syncthreads();
        tmp[threadIdx.x] += a;
        __syncthreads();
    }
    if (threadIdx.x < nb) bsums[threadIdx.x] = tmp[threadIdx.x] - v;  // exclusive
}

__global__ void scan3_kernel(const int* __restrict__ excl, const int* __restrict__ bsums,
                             int* __restrict__ row_ptr, int* __restrict__ cursor,
                             int n, int E) {
    int i = blockIdx.x * 256 + threadIdx.x;
    if (i < n) {
        int v = excl[i] + bsums[i >> 10];
        row_ptr[i] = v;
        cursor[i] = v;
    }
    if (i == n) row_ptr[n] = E;
}

__global__ void scatter_kernel(const int* __restrict__ src, const int* __restrict__ dst,
                               int* __restrict__ cursor, int* __restrict__ srcs, int E) {
    int i = blockIdx.x * blockDim.x + threadIdx.x;
    if (i < E) {
        int pos = atomicAdd(&cursor[dst[i]], 1);
        srcs[pos] = src[i];
    }
}

// W[k][n] fp32 -> Wt[n][k] fp16, 4 matrices. 256 blocks (64/matrix) x 256 thr.
__global__ void convw_kernel(const float* __restrict__ W0, const float* __restrict__ W1,
                             const float* __restrict__ W2, const float* __restrict__ W3,
                             _Float16* __restrict__ T0, _Float16* __restrict__ T1,
                             _Float16* __restrict__ T2, _Float16* __restrict__ T3) {
    int m   = blockIdx.x >> 6;
    int tid = (blockIdx.x & 63) * 256 + threadIdx.x;   // 0..16383 = n*128+k
    int n = tid >> 7, k = tid & 127;
    const float* W = m == 0 ? W0 : m == 1 ? W1 : m == 2 ? W2 : W3;
    _Float16*    T = m == 0 ? T0 : m == 1 ? T1 : m == 2 ? T2 : T3;
    T[tid] = (_Float16)W[k * F + n];
}

// ---------------- MFMA GEMM, LDS-staged B (R10-proven, ~15us/dispatch) ----------------
// grid (nb, 2): blockIdx.y = matrix (0: Wl -> xl fp16, 1: Wr -> xr fp32).
// 256 thr = 4 waves x 16 rows. W^T in LDS, 17-granule row pad -> even bank spread.
// A/B share k-slot map (k = t*32+g*8+j); C/D: col=lane&15, row=(lane>>4)*4+reg.

template<int A_FP32>
__global__ __launch_bounds__(256) void mfma_gemm_kernel(
    const void* __restrict__ Xin,
    const _Float16* __restrict__ Wlt, const float* __restrict__ bl,
    const _Float16* __restrict__ Wrt, const float* __restrict__ br,
    _Float16* __restrict__ xl, float* __restrict__ xr, int N)
{
    const int m = blockIdx.y;
    const _Float16* Wt = m ? Wrt : Wlt;

    __shared__ f16x8 Ws[F * 17];             // 128 rows x (16 data + 1 pad) granules
    for (int i = threadIdx.x; i < F * 16; i += 256) {
        int row = i >> 4, g = i & 15;
        Ws[row * 17 + g] = ((const f16x8*)Wt)[i];
    }
    __syncthreads();

    const int wid  = threadIdx.x >> 6;
    const int lane = threadIdx.x & 63;
    const int row0 = blockIdx.x * 64 + wid * 16;
    const int arow = lane & 15;
    const int g    = lane >> 4;              // 0..3

    int xrow = row0 + arow;
    if (xrow >= N) xrow = N - 1;             // clamp (C stores guarded)
    f16x8 af[4];
    if (A_FP32) {
        const float* xp = (const float*)Xin + (size_t)xrow * F + g * 8;
        #pragma unroll
        for (int t = 0; t < 4; ++t) {
            float4 lo = *(const float4*)(xp + t * 32);
            float4 hi = *(const float4*)(xp + t * 32 + 4);
            f16x8 a;
            a[0] = (_Float16)lo.x; a[1] = (_Float16)lo.y; a[2] = (_Float16)lo.z; a[3] = (_Float16)lo.w;
            a[4] = (_Float16)hi.x; a[5] = (_Float16)hi.y; a[6] = (_Float16)hi.z; a[7] = (_Float16)hi.w;
            af[t] = a;
        }
    } else {
        const _Float16* xp = (const _Float16*)Xin + (size_t)xrow * F + g * 8;
        #pragma unroll
        for (int t = 0; t < 4; ++t)
            af[t] = *(const f16x8*)(xp + t * 32);
    }

    f32x4 acc[8];
    #pragma unroll
    for (int nt = 0; nt < 8; ++nt) acc[nt] = (f32x4){0.f, 0.f, 0.f, 0.f};

    #pragma unroll
    for (int t = 0; t < 4; ++t)
        #pragma unroll
        for (int nt = 0; nt < 8; ++nt) {
            f16x8 b = Ws[(nt * 16 + arow) * 17 + (t * 4 + g)];
            acc[nt] = __builtin_amdgcn_mfma_f32_16x16x32_f16(af[t], b, acc[nt], 0, 0, 0);
        }

    const float* bias = m ? br : bl;
    #pragma unroll
    for (int nt = 0; nt < 8; ++nt) {
        int ccol = nt * 16 + (lane & 15);
        float bv = bias[ccol];
        #pragma unroll
        for (int r2 = 0; r2 < 4; ++r2) {
            int crow = row0 + (lane >> 4) * 4 + r2;
            if (crow < N) {
                float v = acc[nt][r2] + bv;
                if (m == 0) xl[(size_t)crow * F + ccol] = (_Float16)v;
                else        xr[(size_t)crow * F + ccol] = v;
            }
        }
    }
}

// ---------------- fused edge phase v2: 8-channel lanes, 4 edge-slots ----------------
// 1 wave/node, 4 nodes/block. Lane l: es = l>>4 (edge slot), q = l&15 owns channels
// 8q..8q+7 (one 16B fp16 gather/lane; per edge slot 16 lanes x 16B = 256B contiguous).
// Head = q>>2 -> logit reduce = 2 shfls (quad); exp per lane per 4 edges (was per 1).
// Two masked chunks per iteration (8 edges in flight). Plain exp (logits O(5)).
// es-combine (shfl 16/32) once at the end. out_half: layer-1 writes fp16 h.

__global__ __launch_bounds__(256) void gat_edge_kernel(
    const _Float16* __restrict__ xlh, const float* __restrict__ xr,
    const int* __restrict__ srcs, const int* __restrict__ row_ptr,
    const float* __restrict__ att, const float* __restrict__ bias,
    float* __restrict__ outf, _Float16* __restrict__ outh,
    int N, int do_relu, int out_half)
{
    int node = blockIdx.x * 4 + threadIdx.y;
    if (node >= N) return;
    int lane = threadIdx.x;      // 0..63
    int es = lane >> 4;          // edge slot 0..3
    int q  = lane & 15;          // channel-oct: channels 8q..8q+7

    const float* xrp = xr + (size_t)node * F + q * 8;
    float4 xa = *(const float4*)(xrp);
    float4 xb = *(const float4*)(xrp + 4);
    float xr8[8] = {xa.x, xa.y, xa.z, xa.w, xb.x, xb.y, xb.z, xb.w};
    float4 aa = *(const float4*)(att + q * 8);
    float4 ab = *(const float4*)(att + q * 8 + 4);
    float at8[8] = {aa.x, aa.y, aa.z, aa.w, ab.x, ab.y, ab.z, ab.w};

    int beg = row_ptr[node], end = row_ptr[node + 1];
    float s = 0.f;
    float o[8] = {0.f, 0.f, 0.f, 0.f, 0.f, 0.f, 0.f, 0.f};

    for (int i = beg; i < end; i += 8) {
        // chunk A: edges i+es
        int iA = i + es;
        bool vA = iA < end;
        int snA = srcs[vA ? iA : beg];
        f16x8 hA = *(const f16x8*)(xlh + (size_t)snA * F + q * 8);
        // chunk B: edges i+4+es
        int iB = i + 4 + es;
        bool vB = iB < end;
        int snB = srcs[vB ? iB : beg];
        f16x8 hB = *(const f16x8*)(xlh + (size_t)snB * F + q * 8);

        float a[8], b[8];
        #pragma unroll
        for (int j = 0; j < 8; ++j) { a[j] = (float)hA[j]; b[j] = (float)hB[j]; }

        float pA = 0.f, pB = 0.f;
        #pragma unroll
        for (int j = 0; j < 8; ++j) {
            float eA = a[j] + xr8[j];
            eA = fmaxf(eA, 0.2f * eA);          // leaky_relu(slope .2)
            pA = fmaf(eA, at8[j], pA);
            float eB = b[j] + xr8[j];
            eB = fmaxf(eB, 0.2f * eB);
            pB = fmaf(eB, at8[j], pB);
        }
        pA += __shfl_xor(pA, 1); pA += __shfl_xor(pA, 2);   // head quad reduce
        pB += __shfl_xor(pB, 1); pB += __shfl_xor(pB, 2);
        float wA = vA ? __expf(pA) : 0.f;
        float wB = vB ? __expf(pB) : 0.f;
        s += wA + wB;
        #pragma unroll
        for (int j = 0; j < 8; ++j) {
            o[j] = fmaf(wA, a[j], o[j]);
            o[j] = fmaf(wB, b[j], o[j]);
        }
    }

    // combine the 4 edge slots
    s += __shfl_xor(s, 16); s += __shfl_xor(s, 32);
    #pragma unroll
    for (int j = 0; j < 8; ++j) {
        o[j] += __shfl_xor(o[j], 16);
        o[j] += __shfl_xor(o[j], 32);
    }

    if (es == 0) {
        float inv = 1.f / (s + 1e-16f);
        float r[8];
        #pragma unroll
        for (int j = 0; j < 8; ++j) {
            r[j] = fmaf(o[j], inv, bias[q * 8 + j]);
            if (do_relu) r[j] = fmaxf(r[j], 0.f);
        }
        if (out_half) {
            f16x8 hv;
            #pragma unroll
            for (int j = 0; j < 8; ++j) hv[j] = (_Float16)r[j];
            *(f16x8*)(outh + (size_t)node * F + q * 8) = hv;
        } else {
            float4 lo = {r[0], r[1], r[2], r[3]};
            float4 hi = {r[4], r[5], r[6], r[7]};
            *(float4*)(outf + (size_t)node * F + q * 8) = lo;
            *(float4*)(outf + (size_t)node * F + q * 8 + 4) = hi;
        }
    }
}

// ---------------- launch ----------------

extern "C" void kernel_launch(void* const* d_in, const int* in_sizes, int n_in,
                              void* d_out, int out_size, void* d_ws, size_t ws_size,
                              hipStream_t stream)
{
    const float* x    = (const float*)d_in[0];
    const int*   ei   = (const int*)d_in[1];
    const float* Wl1  = (const float*)d_in[2];
    const float* Wr1  = (const float*)d_in[3];
    const float* Wl2  = (const float*)d_in[4];
    const float* Wr2  = (const float*)d_in[5];
    const float* bl1  = (const float*)d_in[6];
    const float* br1  = (const float*)d_in[7];
    const float* bl2  = (const float*)d_in[8];
    const float* br2  = (const float*)d_in[9];
    const float* att1 = (const float*)d_in[10];
    const float* att2 = (const float*)d_in[11];
    const float* b1   = (const float*)d_in[12];
    const float* b2   = (const float*)d_in[13];

    const int N = in_sizes[0] / F;
    const int E = in_sizes[1] / 2;
    const int* src = ei;
    const int* dst = ei + E;

    char* ws = (char*)d_ws;
    size_t off = 0;
    auto alloc = [&](size_t bytes) -> void* {
        void* p = ws + off;
        off = (off + bytes + 255) & ~(size_t)255;
        return p;
    };
    _Float16* hh   = (_Float16*)alloc((size_t)N * F * sizeof(_Float16));  // fp16 h (layer2 in)
    _Float16* xlh  = (_Float16*)alloc((size_t)N * F * sizeof(_Float16));  // fp16 xl
    float*    xr   = (float*)alloc((size_t)N * F * sizeof(float));        // fp32 xr
    _Float16* Wt1l = (_Float16*)alloc((size_t)F * F * sizeof(_Float16));
    _Float16* Wt1r = (_Float16*)alloc((size_t)F * F * sizeof(_Float16));
    _Float16* Wt2l = (_Float16*)alloc((size_t)F * F * sizeof(_Float16));
    _Float16* Wt2r = (_Float16*)alloc((size_t)F * F * sizeof(_Float16));
    int* row_ptr   = (int*)alloc((size_t)(N + 1) * sizeof(int));
    int* deg       = (int*)alloc((size_t)N * sizeof(int));
    int* excl      = (int*)alloc((size_t)N * sizeof(int));
    int* bsums     = (int*)alloc((size_t)1024 * sizeof(int));
    int* cursor    = (int*)alloc((size_t)N * sizeof(int));
    int* srcs      = (int*)alloc((size_t)E * sizeof(int));

    // CSR build
    hipMemsetAsync(deg, 0, (size_t)N * sizeof(int), stream);
    count_deg_kernel<<<(E + 255) / 256, 256, 0, stream>>>(dst, deg, E);
    const int nchunks = (N + 1023) / 1024;
    scan1_kernel<<<nchunks, 1024, 0, stream>>>(deg, excl, bsums, N);
    scan2_kernel<<<1, 1024, 0, stream>>>(bsums, nchunks);
    scan3_kernel<<<(N + 256) / 256, 256, 0, stream>>>(excl, bsums, row_ptr, cursor, N, E);
    scatter_kernel<<<(E + 255) / 256, 256, 0, stream>>>(src, dst, cursor, srcs, E);

    // weight transpose+convert
    convw_kernel<<<256, 256, 0, stream>>>(Wl1, Wr1, Wl2, Wr2, Wt1l, Wt1r, Wt2l, Wt2r);

    const int gemm_blocks = (N + 63) / 64;
    dim3 gemm_grid(gemm_blocks, 2);
    dim3 eb(64, 4);
    const int edge_blocks = (N + 3) / 4;

    // layer 1 (A fp32, converted inline)
    mfma_gemm_kernel<1><<<gemm_grid, 256, 0, stream>>>(
        x, Wt1l, bl1, Wt1r, br1, xlh, xr, N);
    gat_edge_kernel<<<edge_blocks, eb, 0, stream>>>(
        xlh, xr, srcs, row_ptr, att1, b1, nullptr, hh, N, 1, 1);

    // layer 2 (A fp16 from edge layer 1)
    mfma_gemm_kernel<0><<<gemm_grid, 256, 0, stream>>>(
        hh, Wt2l, bl2, Wt2r, br2, xlh, xr, N);
    gat_edge_kernel<<<edge_blocks, eb, 0, stream>>>(
        xlh, xr, srcs, row_ptr, att2, b2, (float*)d_out, nullptr, N, 0, 0);
}

// Round 12
// 175.630 us; speedup vs baseline: 2.1904x; 1.3588x over previous
//
#include <hip/hip_runtime.h>
#include <hip/hip_bf16.h>
#include <hip/hip_fp16.h>
#include <float.h>

#define F 128          // hidden = H*C
#define HEADS 4
#define CPH 32

// bucket sort params: bucket = dst>>7 (needs N <= 65536; N=50000), 512 buckets,
// G=64 edge-chunk blocks -> counts matrix 512x64 = 32768.
#define NB 512
#define BSHIFT 7
#define G 64

using f16x8 = __attribute__((ext_vector_type(8))) _Float16;
using f32x4 = __attribute__((ext_vector_type(4))) float;

// ---------------- bucketed CSR build ----------------
// R11 showed scatter_kernel = 55us with WRITE_SIZE 52MB for a 3.2MB array (16x
// write amplification: random 4B scatters from 8 XCDs dirty 64B lines partially).
// Counting sort by dst>>7 keeps every write window block-private and contiguous.

// pass A: per-block bucket histogram
__global__ __launch_bounds__(1024) void bucket_hist_kernel(
    const int* __restrict__ dst, int* __restrict__ counts, int E, int chunk)
{
    __shared__ int hist[NB];
    int blk = blockIdx.x;
    for (int b = threadIdx.x; b < NB; b += 1024) hist[b] = 0;
    __syncthreads();
    int e0 = blk * chunk, e1 = min(e0 + chunk, E);
    for (int e = e0 + threadIdx.x; e < e1; e += 1024)
        atomicAdd(&hist[dst[e] >> BSHIFT], 1);
    __syncthreads();
    for (int b = threadIdx.x; b < NB; b += 1024)
        counts[b * G + blk] = hist[b];
}

// pass B: hierarchical exclusive scan of counts (n = NB*G = 32768)
__global__ __launch_bounds__(1024) void scan1_kernel(const int* __restrict__ in,
                                                     int* __restrict__ excl,
                                                     int* __restrict__ bsums, int n) {
    __shared__ int tmp[1024];
    int i = blockIdx.x * 1024 + threadIdx.x;
    int v = (i < n) ? in[i] : 0;
    tmp[threadIdx.x] = v;
    __syncthreads();
    for (int o = 1; o < 1024; o <<= 1) {
        int a = (threadIdx.x >= o) ? tmp[threadIdx.x - o] : 0;
        __syncthreads();
        tmp[threadIdx.x] += a;
        __syncthreads();
    }
    if (i < n) excl[i] = tmp[threadIdx.x] - v;
    if (threadIdx.x == 1023) bsums[blockIdx.x] = tmp[1023];
}

__global__ __launch_bounds__(1024) void scan2_kernel(int* __restrict__ bsums, int nb) {
    __shared__ int tmp[1024];
    int v = (threadIdx.x < nb) ? bsums[threadIdx.x] : 0;
    tmp[threadIdx.x] = v;
    __syncthreads();
    for (int o = 1; o < 1024; o <<= 1) {
        int a = (threadIdx.x >= o) ? tmp[threadIdx.x - o] : 0;
        __syncthreads();
        tmp[threadIdx.x] += a;
        __syncthreads();
    }
    if (threadIdx.x < nb) bsums[threadIdx.x] = tmp[threadIdx.x] - v;  // exclusive
}

__global__ __launch_bounds__(1024) void addback_kernel(const int* __restrict__ excl,
                                                       const int* __restrict__ bsums,
                                                       int* __restrict__ offsets, int n) {
    int i = blockIdx.x * 1024 + threadIdx.x;
    if (i < n) offsets[i] = excl[i] + bsums[i >> 10];
}

// pass C: scatter (src,dst) pairs into bucket-sorted order via LDS cursors
__global__ __launch_bounds__(1024) void bucket_scatter_kernel(
    const int* __restrict__ src, const int* __restrict__ dst,
    const int* __restrict__ offsets, uint2* __restrict__ pairs, int E, int chunk)
{
    __shared__ int curs[NB];
    int blk = blockIdx.x;
    for (int b = threadIdx.x; b < NB; b += 1024) curs[b] = offsets[b * G + blk];
    __syncthreads();
    int e0 = blk * chunk, e1 = min(e0 + chunk, E);
    for (int e = e0 + threadIdx.x; e < e1; e += 1024) {
        int d = dst[e];
        int pos = atomicAdd(&curs[d >> BSHIFT], 1);
        pairs[pos] = make_uint2((unsigned)src[e], (unsigned)d);
    }
}

// pass D: per-bucket (128 nodes) local hist + scan -> row_ptr AND final srcs,
// all writes into the block-private contiguous segment.
__global__ __launch_bounds__(256) void bucket_csr_kernel(
    const uint2* __restrict__ pairs, const int* __restrict__ offsets,
    int* __restrict__ row_ptr, int* __restrict__ srcs, int N, int E)
{
    int b = blockIdx.x;                    // 0..NB-1
    int seg0 = offsets[b * G];
    int seg1 = (b < NB - 1) ? offsets[(b + 1) * G] : E;
    __shared__ int hist[128], curs[128];
    if (threadIdx.x < 128) hist[threadIdx.x] = 0;
    __syncthreads();
    for (int e = seg0 + threadIdx.x; e < seg1; e += 256)
        atomicAdd(&hist[pairs[e].y & 127], 1);
    __syncthreads();
    int v = (threadIdx.x < 128) ? hist[threadIdx.x] : 0;
    if (threadIdx.x < 128) curs[threadIdx.x] = v;
    __syncthreads();
    for (int o = 1; o < 128; o <<= 1) {
        int a = 0;
        if (threadIdx.x < 128 && threadIdx.x >= o) a = curs[threadIdx.x - o];
        __syncthreads();
        if (threadIdx.x < 128) curs[threadIdx.x] += a;
        __syncthreads();
    }
    int excl = (threadIdx.x < 128) ? curs[threadIdx.x] - v : 0;
    __syncthreads();
    if (threadIdx.x < 128) {
        int node = b * 128 + threadIdx.x;
        if (node <= N) row_ptr[node] = seg0 + excl;   // node==N lands on E (trailing buckets empty)
        curs[threadIdx.x] = excl;
    }
    __syncthreads();
    for (int e = seg0 + threadIdx.x; e < seg1; e += 256) {
        uint2 p = pairs[e];
        int pos = seg0 + atomicAdd(&curs[p.y & 127], 1);
        srcs[pos] = (int)p.x;
    }
}

// W[k][n] fp32 -> Wt[n][k] fp16, 4 matrices. 256 blocks (64/matrix) x 256 thr.
__global__ void convw_kernel(const float* __restrict__ W0, const float* __restrict__ W1,
                             const float* __restrict__ W2, const float* __restrict__ W3,
                             _Float16* __restrict__ T0, _Float16* __restrict__ T1,
                             _Float16* __restrict__ T2, _Float16* __restrict__ T3) {
    int m   = blockIdx.x >> 6;
    int tid = (blockIdx.x & 63) * 256 + threadIdx.x;   // 0..16383 = n*128+k
    int n = tid >> 7, k = tid & 127;
    const float* W = m == 0 ? W0 : m == 1 ? W1 : m == 2 ? W2 : W3;
    _Float16*    T = m == 0 ? T0 : m == 1 ? T1 : m == 2 ? T2 : T3;
    T[tid] = (_Float16)W[k * F + n];
}

// ---------------- MFMA GEMM, LDS-staged B (R10-proven) ----------------
// grid (nb, 2): blockIdx.y = matrix (0: Wl -> xl fp16, 1: Wr -> xr fp32).
// 256 thr = 4 waves x 16 rows. W^T in LDS, 17-granule row pad.
// A/B share k-slot map (k = t*32+g*8+j); C/D: col=lane&15, row=(lane>>4)*4+reg.

template<int A_FP32>
__global__ __launch_bounds__(256) void mfma_gemm_kernel(
    const void* __restrict__ Xin,
    const _Float16* __restrict__ Wlt, const float* __restrict__ bl,
    const _Float16* __restrict__ Wrt, const float* __restrict__ br,
    _Float16* __restrict__ xl, float* __restrict__ xr, int N)
{
    const int m = blockIdx.y;
    const _Float16* Wt = m ? Wrt : Wlt;

    __shared__ f16x8 Ws[F * 17];             // 128 rows x (16 data + 1 pad) granules
    for (int i = threadIdx.x; i < F * 16; i += 256) {
        int row = i >> 4, g = i & 15;
        Ws[row * 17 + g] = ((const f16x8*)Wt)[i];
    }
    __syncthreads();

    const int wid  = threadIdx.x >> 6;
    const int lane = threadIdx.x & 63;
    const int row0 = blockIdx.x * 64 + wid * 16;
    const int arow = lane & 15;
    const int g    = lane >> 4;              // 0..3

    int xrow = row0 + arow;
    if (xrow >= N) xrow = N - 1;             // clamp (C stores guarded)
    f16x8 af[4];
    if (A_FP32) {
        const float* xp = (const float*)Xin + (size_t)xrow * F + g * 8;
        #pragma unroll
        for (int t = 0; t < 4; ++t) {
            float4 lo = *(const float4*)(xp + t * 32);
            float4 hi = *(const float4*)(xp + t * 32 + 4);
            f16x8 a;
            a[0] = (_Float16)lo.x; a[1] = (_Float16)lo.y; a[2] = (_Float16)lo.z; a[3] = (_Float16)lo.w;
            a[4] = (_Float16)hi.x; a[5] = (_Float16)hi.y; a[6] = (_Float16)hi.z; a[7] = (_Float16)hi.w;
            af[t] = a;
        }
    } else {
        const _Float16* xp = (const _Float16*)Xin + (size_t)xrow * F + g * 8;
        #pragma unroll
        for (int t = 0; t < 4; ++t)
            af[t] = *(const f16x8*)(xp + t * 32);
    }

    f32x4 acc[8];
    #pragma unroll
    for (int nt = 0; nt < 8; ++nt) acc[nt] = (f32x4){0.f, 0.f, 0.f, 0.f};

    #pragma unroll
    for (int t = 0; t < 4; ++t)
        #pragma unroll
        for (int nt = 0; nt < 8; ++nt) {
            f16x8 b = Ws[(nt * 16 + arow) * 17 + (t * 4 + g)];
            acc[nt] = __builtin_amdgcn_mfma_f32_16x16x32_f16(af[t], b, acc[nt], 0, 0, 0);
        }

    const float* bias = m ? br : bl;
    #pragma unroll
    for (int nt = 0; nt < 8; ++nt) {
        int ccol = nt * 16 + (lane & 15);
        float bv = bias[ccol];
        #pragma unroll
        for (int r2 = 0; r2 < 4; ++r2) {
            int crow = row0 + (lane >> 4) * 4 + r2;
            if (crow < N) {
                float v = acc[nt][r2] + bv;
                if (m == 0) xl[(size_t)crow * F + ccol] = (_Float16)v;
                else        xr[(size_t)crow * F + ccol] = v;
            }
        }
    }
}

// ---------------- fused edge phase v2 (R11-proven): 8-ch lanes, 4 edge-slots --------
// 1 wave/node, 4 nodes/block. Lane l: es = l>>4 (edge slot), q = l&15 owns channels
// 8q..8q+7 (16B fp16 gather/lane). Head = q>>2 -> 2-shfl quad reduce; exp per 4 edges.
// Two masked chunks per iteration (8 edges in flight). Plain exp (logits O(5)).

__global__ __launch_bounds__(256) void gat_edge_kernel(
    const _Float16* __restrict__ xlh, const float* __restrict__ xr,
    const int* __restrict__ srcs, const int* __restrict__ row_ptr,
    const float* __restrict__ att, const float* __restrict__ bias,
    float* __restrict__ outf, _Float16* __restrict__ outh,
    int N, int do_relu, int out_half)
{
    int node = blockIdx.x * 4 + threadIdx.y;
    if (node >= N) return;
    int lane = threadIdx.x;      // 0..63
    int es = lane >> 4;          // edge slot 0..3
    int q  = lane & 15;          // channel-oct: channels 8q..8q+7

    const float* xrp = xr + (size_t)node * F + q * 8;
    float4 xa = *(const float4*)(xrp);
    float4 xb = *(const float4*)(xrp + 4);
    float xr8[8] = {xa.x, xa.y, xa.z, xa.w, xb.x, xb.y, xb.z, xb.w};
    float4 aa = *(const float4*)(att + q * 8);
    float4 ab = *(const float4*)(att + q * 8 + 4);
    float at8[8] = {aa.x, aa.y, aa.z, aa.w, ab.x, ab.y, ab.z, ab.w};

    int beg = row_ptr[node], end = row_ptr[node + 1];
    float s = 0.f;
    float o[8] = {0.f, 0.f, 0.f, 0.f, 0.f, 0.f, 0.f, 0.f};

    for (int i = beg; i < end; i += 8) {
        int iA = i + es;
        bool vA = iA < end;
        int snA = srcs[vA ? iA : beg];
        f16x8 hA = *(const f16x8*)(xlh + (size_t)snA * F + q * 8);
        int iB = i + 4 + es;
        bool vB = iB < end;
        int snB = srcs[vB ? iB : beg];
        f16x8 hB = *(const f16x8*)(xlh + (size_t)snB * F + q * 8);

        float a[8], b[8];
        #pragma unroll
        for (int j = 0; j < 8; ++j) { a[j] = (float)hA[j]; b[j] = (float)hB[j]; }

        float pA = 0.f, pB = 0.f;
        #pragma unroll
        for (int j = 0; j < 8; ++j) {
            float eA = a[j] + xr8[j];
            eA = fmaxf(eA, 0.2f * eA);          // leaky_relu(slope .2)
            pA = fmaf(eA, at8[j], pA);
            float eB = b[j] + xr8[j];
            eB = fmaxf(eB, 0.2f * eB);
            pB = fmaf(eB, at8[j], pB);
        }
        pA += __shfl_xor(pA, 1); pA += __shfl_xor(pA, 2);   // head quad reduce
        pB += __shfl_xor(pB, 1); pB += __shfl_xor(pB, 2);
        float wA = vA ? __expf(pA) : 0.f;
        float wB = vB ? __expf(pB) : 0.f;
        s += wA + wB;
        #pragma unroll
        for (int j = 0; j < 8; ++j) {
            o[j] = fmaf(wA, a[j], o[j]);
            o[j] = fmaf(wB, b[j], o[j]);
        }
    }

    s += __shfl_xor(s, 16); s += __shfl_xor(s, 32);
    #pragma unroll
    for (int j = 0; j < 8; ++j) {
        o[j] += __shfl_xor(o[j], 16);
        o[j] += __shfl_xor(o[j], 32);
    }

    if (es == 0) {
        float inv = 1.f / (s + 1e-16f);
        float r[8];
        #pragma unroll
        for (int j = 0; j < 8; ++j) {
            r[j] = fmaf(o[j], inv, bias[q * 8 + j]);
            if (do_relu) r[j] = fmaxf(r[j], 0.f);
        }
        if (out_half) {
            f16x8 hv;
            #pragma unroll
            for (int j = 0; j < 8; ++j) hv[j] = (_Float16)r[j];
            *(f16x8*)(outh + (size_t)node * F + q * 8) = hv;
        } else {
            float4 lo = {r[0], r[1], r[2], r[3]};
            float4 hi = {r[4], r[5], r[6], r[7]};
            *(float4*)(outf + (size_t)node * F + q * 8) = lo;
            *(float4*)(outf + (size_t)node * F + q * 8 + 4) = hi;
        }
    }
}

// ---------------- launch ----------------

extern "C" void kernel_launch(void* const* d_in, const int* in_sizes, int n_in,
                              void* d_out, int out_size, void* d_ws, size_t ws_size,
                              hipStream_t stream)
{
    const float* x    = (const float*)d_in[0];
    const int*   ei   = (const int*)d_in[1];
    const float* Wl1  = (const float*)d_in[2];
    const float* Wr1  = (const float*)d_in[3];
    const float* Wl2  = (const float*)d_in[4];
    const float* Wr2  = (const float*)d_in[5];
    const float* bl1  = (const float*)d_in[6];
    const float* br1  = (const float*)d_in[7];
    const float* bl2  = (const float*)d_in[8];
    const float* br2  = (const float*)d_in[9];
    const float* att1 = (const float*)d_in[10];
    const float* att2 = (const float*)d_in[11];
    const float* b1   = (const float*)d_in[12];
    const float* b2   = (const float*)d_in[13];

    const int N = in_sizes[0] / F;
    const int E = in_sizes[1] / 2;
    const int* src = ei;
    const int* dst = ei + E;

    char* ws = (char*)d_ws;
    size_t off = 0;
    auto alloc = [&](size_t bytes) -> void* {
        void* p = ws + off;
        off = (off + bytes + 255) & ~(size_t)255;
        return p;
    };
    _Float16* hh   = (_Float16*)alloc((size_t)N * F * sizeof(_Float16));  // fp16 h (layer2 in)
    _Float16* xlh  = (_Float16*)alloc((size_t)N * F * sizeof(_Float16));  // fp16 xl
    float*    xr   = (float*)alloc((size_t)N * F * sizeof(float));        // fp32 xr
    _Float16* Wt1l = (_Float16*)alloc((size_t)F * F * sizeof(_Float16));
    _Float16* Wt1r = (_Float16*)alloc((size_t)F * F * sizeof(_Float16));
    _Float16* Wt2l = (_Float16*)alloc((size_t)F * F * sizeof(_Float16));
    _Float16* Wt2r = (_Float16*)alloc((size_t)F * F * sizeof(_Float16));
    int*   row_ptr = (int*)alloc((size_t)(N + 1) * sizeof(int));
    int*   counts  = (int*)alloc((size_t)NB * G * sizeof(int));
    int*   cexcl   = (int*)alloc((size_t)NB * G * sizeof(int));
    int*   bsums   = (int*)alloc((size_t)1024 * sizeof(int));
    int*   offsets = (int*)alloc((size_t)NB * G * sizeof(int));
    uint2* pairs   = (uint2*)alloc((size_t)E * sizeof(uint2));
    int*   srcs    = (int*)alloc((size_t)E * sizeof(int));

    // bucketed CSR build (no global atomics, block-private write windows)
    const int chunk = (E + G - 1) / G;
    const int ncounts = NB * G;                       // 32768
    bucket_hist_kernel<<<G, 1024, 0, stream>>>(dst, counts, E, chunk);
    scan1_kernel<<<ncounts / 1024, 1024, 0, stream>>>(counts, cexcl, bsums, ncounts);
    scan2_kernel<<<1, 1024, 0, stream>>>(bsums, ncounts / 1024);
    addback_kernel<<<ncounts / 1024, 1024, 0, stream>>>(cexcl, bsums, offsets, ncounts);
    bucket_scatter_kernel<<<G, 1024, 0, stream>>>(src, dst, offsets, pairs, E, chunk);
    bucket_csr_kernel<<<NB, 256, 0, stream>>>(pairs, offsets, row_ptr, srcs, N, E);

    // weight transpose+convert
    convw_kernel<<<256, 256, 0, stream>>>(Wl1, Wr1, Wl2, Wr2, Wt1l, Wt1r, Wt2l, Wt2r);

    const int gemm_blocks = (N + 63) / 64;
    dim3 gemm_grid(gemm_blocks, 2);
    dim3 eb(64, 4);
    const int edge_blocks = (N + 3) / 4;

    // layer 1 (A fp32, converted inline)
    mfma_gemm_kernel<1><<<gemm_grid, 256, 0, stream>>>(
        x, Wt1l, bl1, Wt1r, br1, xlh, xr, N);
    gat_edge_kernel<<<edge_blocks, eb, 0, stream>>>(
        xlh, xr, srcs, row_ptr, att1, b1, nullptr, hh, N, 1, 1);

    // layer 2 (A fp16 from edge layer 1)
    mfma_gemm_kernel<0><<<gemm_grid, 256, 0, stream>>>(
        hh, Wt2l, bl2, Wt2r, br2, xlh, xr, N);
    gat_edge_kernel<<<edge_blocks, eb, 0, stream>>>(
        xlh, xr, srcs, row_ptr, att2, b2, (float*)d_out, nullptr, N, 0, 0);
}

// Round 13
// 167.564 us; speedup vs baseline: 2.2958x; 1.0481x over previous
//
#include <hip/hip_runtime.h>
#include <hip/hip_bf16.h>
#include <hip/hip_fp16.h>
#include <float.h>

#define F 128          // hidden = H*C
#define HEADS 4
#define CPH 32

// bucket sort params: bucket = dst>>7 (N=50000 <= 65536), 512 buckets,
// G=64 edge-chunk blocks -> counts matrix 512x64 = 32768.
#define NB 512
#define BSHIFT 7
#define G 64

using f16x2 = __attribute__((ext_vector_type(2))) _Float16;
using f16x8 = __attribute__((ext_vector_type(8))) _Float16;
using f32x4 = __attribute__((ext_vector_type(4))) float;

// ---------------- fused bucket-hist + weight convert ----------------
// blocks 0..G-1: per-block bucket histogram of dst>>7.
// blocks G..G+63: W[k][n] fp32 -> Wt[n][k] fp16 (4 matrices x 16 chunks).

__global__ __launch_bounds__(1024) void hist_convw_kernel(
    const int* __restrict__ dst, int* __restrict__ counts, int E, int chunk,
    const float* __restrict__ W0, const float* __restrict__ W1,
    const float* __restrict__ W2, const float* __restrict__ W3,
    _Float16* __restrict__ T0, _Float16* __restrict__ T1,
    _Float16* __restrict__ T2, _Float16* __restrict__ T3)
{
    __shared__ int hist[NB];
    if (blockIdx.x < G) {
        int blk = blockIdx.x;
        for (int b = threadIdx.x; b < NB; b += 1024) hist[b] = 0;
        __syncthreads();
        int e0 = blk * chunk, e1 = min(e0 + chunk, E);
        for (int e = e0 + threadIdx.x; e < e1; e += 1024)
            atomicAdd(&hist[dst[e] >> BSHIFT], 1);
        __syncthreads();
        for (int b = threadIdx.x; b < NB; b += 1024)
            counts[b * G + blk] = hist[b];
    } else {
        int b = blockIdx.x - G;                       // 0..63
        int m = b >> 4;
        int tid = (b & 15) * 1024 + threadIdx.x;      // 0..16383 = n*128+k
        int n = tid >> 7, k = tid & 127;
        const float* W = m == 0 ? W0 : m == 1 ? W1 : m == 2 ? W2 : W3;
        _Float16*    T = m == 0 ? T0 : m == 1 ? T1 : m == 2 ? T2 : T3;
        T[tid] = (_Float16)W[k * F + n];
    }
}

// ---------------- fused single-block scan of counts (32768 = 1024 x 32) ----------------

__global__ __launch_bounds__(1024) void scan_fused_kernel(
    const int* __restrict__ counts, int* __restrict__ offsets)
{
    __shared__ int tmp[1024];
    int t = threadIdx.x;
    int loc[32];
    int s = 0;
    #pragma unroll
    for (int j = 0; j < 32; ++j) { loc[j] = s; s += counts[t * 32 + j]; }
    tmp[t] = s;
    __syncthreads();
    for (int o = 1; o < 1024; o <<= 1) {
        int a = (t >= o) ? tmp[t - o] : 0;
        __syncthreads();
        tmp[t] += a;
        __syncthreads();
    }
    int excl = tmp[t] - s;
    #pragma unroll
    for (int j = 0; j < 32; ++j) offsets[t * 32 + j] = excl + loc[j];
}

// pass C: scatter (src,dst) pairs into bucket-sorted order via LDS cursors
__global__ __launch_bounds__(1024) void bucket_scatter_kernel(
    const int* __restrict__ src, const int* __restrict__ dst,
    const int* __restrict__ offsets, uint2* __restrict__ pairs, int E, int chunk)
{
    __shared__ int curs[NB];
    int blk = blockIdx.x;
    for (int b = threadIdx.x; b < NB; b += 1024) curs[b] = offsets[b * G + blk];
    __syncthreads();
    int e0 = blk * chunk, e1 = min(e0 + chunk, E);
    for (int e = e0 + threadIdx.x; e < e1; e += 1024) {
        int d = dst[e];
        int pos = atomicAdd(&curs[d >> BSHIFT], 1);
        pairs[pos] = make_uint2((unsigned)src[e], (unsigned)d);
    }
}

// pass D: per-bucket local hist + scan -> row_ptr AND final srcs (block-private segment)
__global__ __launch_bounds__(256) void bucket_csr_kernel(
    const uint2* __restrict__ pairs, const int* __restrict__ offsets,
    int* __restrict__ row_ptr, int* __restrict__ srcs, int N, int E)
{
    int b = blockIdx.x;                    // 0..NB-1
    int seg0 = offsets[b * G];
    int seg1 = (b < NB - 1) ? offsets[(b + 1) * G] : E;
    __shared__ int hist[128], curs[128];
    if (threadIdx.x < 128) hist[threadIdx.x] = 0;
    __syncthreads();
    for (int e = seg0 + threadIdx.x; e < seg1; e += 256)
        atomicAdd(&hist[pairs[e].y & 127], 1);
    __syncthreads();
    int v = (threadIdx.x < 128) ? hist[threadIdx.x] : 0;
    if (threadIdx.x < 128) curs[threadIdx.x] = v;
    __syncthreads();
    for (int o = 1; o < 128; o <<= 1) {
        int a = 0;
        if (threadIdx.x < 128 && threadIdx.x >= o) a = curs[threadIdx.x - o];
        __syncthreads();
        if (threadIdx.x < 128) curs[threadIdx.x] += a;
        __syncthreads();
    }
    int excl = (threadIdx.x < 128) ? curs[threadIdx.x] - v : 0;
    __syncthreads();
    if (threadIdx.x < 128) {
        int node = b * 128 + threadIdx.x;
        if (node <= N) row_ptr[node] = seg0 + excl;
        curs[threadIdx.x] = excl;
    }
    __syncthreads();
    for (int e = seg0 + threadIdx.x; e < seg1; e += 256) {
        uint2 p = pairs[e];
        int pos = seg0 + atomicAdd(&curs[p.y & 127], 1);
        srcs[pos] = (int)p.x;
    }
}

// ---------------- MFMA GEMM, LDS-staged B (R10-proven) ----------------
// grid (nb, 2): blockIdx.y = matrix (0: Wl -> xl fp16, 1: Wr -> xr fp32).
// 256 thr = 4 waves x 16 rows. W^T in LDS, 17-granule row pad.
// A/B share k-slot map (k = t*32+g*8+j); C/D: col=lane&15, row=(lane>>4)*4+reg.

template<int A_FP32>
__global__ __launch_bounds__(256) void mfma_gemm_kernel(
    const void* __restrict__ Xin,
    const _Float16* __restrict__ Wlt, const float* __restrict__ bl,
    const _Float16* __restrict__ Wrt, const float* __restrict__ br,
    _Float16* __restrict__ xl, float* __restrict__ xr, int N)
{
    const int m = blockIdx.y;
    const _Float16* Wt = m ? Wrt : Wlt;

    __shared__ f16x8 Ws[F * 17];             // 128 rows x (16 data + 1 pad) granules
    for (int i = threadIdx.x; i < F * 16; i += 256) {
        int row = i >> 4, g = i & 15;
        Ws[row * 17 + g] = ((const f16x8*)Wt)[i];
    }
    __syncthreads();

    const int wid  = threadIdx.x >> 6;
    const int lane = threadIdx.x & 63;
    const int row0 = blockIdx.x * 64 + wid * 16;
    const int arow = lane & 15;
    const int g    = lane >> 4;              // 0..3

    int xrow = row0 + arow;
    if (xrow >= N) xrow = N - 1;             // clamp (C stores guarded)
    f16x8 af[4];
    if (A_FP32) {
        const float* xp = (const float*)Xin + (size_t)xrow * F + g * 8;
        #pragma unroll
        for (int t = 0; t < 4; ++t) {
            float4 lo = *(const float4*)(xp + t * 32);
            float4 hi = *(const float4*)(xp + t * 32 + 4);
            f16x8 a;
            a[0] = (_Float16)lo.x; a[1] = (_Float16)lo.y; a[2] = (_Float16)lo.z; a[3] = (_Float16)lo.w;
            a[4] = (_Float16)hi.x; a[5] = (_Float16)hi.y; a[6] = (_Float16)hi.z; a[7] = (_Float16)hi.w;
            af[t] = a;
        }
    } else {
        const _Float16* xp = (const _Float16*)Xin + (size_t)xrow * F + g * 8;
        #pragma unroll
        for (int t = 0; t < 4; ++t)
            af[t] = *(const f16x8*)(xp + t * 32);
    }

    f32x4 acc[8];
    #pragma unroll
    for (int nt = 0; nt < 8; ++nt) acc[nt] = (f32x4){0.f, 0.f, 0.f, 0.f};

    #pragma unroll
    for (int t = 0; t < 4; ++t)
        #pragma unroll
        for (int nt = 0; nt < 8; ++nt) {
            f16x8 b = Ws[(nt * 16 + arow) * 17 + (t * 4 + g)];
            acc[nt] = __builtin_amdgcn_mfma_f32_16x16x32_f16(af[t], b, acc[nt], 0, 0, 0);
        }

    const float* bias = m ? br : bl;
    #pragma unroll
    for (int nt = 0; nt < 8; ++nt) {
        int ccol = nt * 16 + (lane & 15);
        float bv = bias[ccol];
        #pragma unroll
        for (int r2 = 0; r2 < 4; ++r2) {
            int crow = row0 + (lane >> 4) * 4 + r2;
            if (crow < N) {
                float v = acc[nt][r2] + bv;
                if (m == 0) xl[(size_t)crow * F + ccol] = (_Float16)v;
                else        xr[(size_t)crow * F + ccol] = v;
            }
        }
    }
}

// ---------------- fused edge phase v3: packed-fp16 logit ----------------
// 1 wave/node, 4 nodes/block. Lane: es = l>>4 (edge slot), q = l&15 owns channels
// 8q..8q+7 (16B fp16 gather). Logit per 2ch: pk_add, pk_mul, pk_max, pk_fma (f16x2
// accumulate, |p|<~4 so ulp ~4e-3 -> <0.5% weight perturbation). o accumulates fp32
// via fma_mix. 8 edge-slots/iter (82% slot utilization), unroll 2 -> 4 gathers in flight.

__global__ __launch_bounds__(256) void gat_edge_kernel(
    const _Float16* __restrict__ xlh, const float* __restrict__ xr,
    const int* __restrict__ srcs, const int* __restrict__ row_ptr,
    const float* __restrict__ att, const float* __restrict__ bias,
    float* __restrict__ outf, _Float16* __restrict__ outh,
    int N, int do_relu, int out_half)
{
    int node = blockIdx.x * 4 + threadIdx.y;
    if (node >= N) return;
    int lane = threadIdx.x;      // 0..63
    int es = lane >> 4;          // edge slot 0..3
    int q  = lane & 15;          // channel-oct: channels 8q..8q+7

    const float* xrp = xr + (size_t)node * F + q * 8;
    float4 xa = *(const float4*)(xrp);
    float4 xb = *(const float4*)(xrp + 4);
    f16x2 xrh[4] = { {(_Float16)xa.x, (_Float16)xa.y}, {(_Float16)xa.z, (_Float16)xa.w},
                     {(_Float16)xb.x, (_Float16)xb.y}, {(_Float16)xb.z, (_Float16)xb.w} };
    float4 aa = *(const float4*)(att + q * 8);
    float4 ab = *(const float4*)(att + q * 8 + 4);
    f16x2 ath[4] = { {(_Float16)aa.x, (_Float16)aa.y}, {(_Float16)aa.z, (_Float16)aa.w},
                     {(_Float16)ab.x, (_Float16)ab.y}, {(_Float16)ab.z, (_Float16)ab.w} };
    const f16x2 slope = {(_Float16)0.2f, (_Float16)0.2f};

    int beg = row_ptr[node], end = row_ptr[node + 1];
    float s = 0.f;
    float o[8] = {0.f, 0.f, 0.f, 0.f, 0.f, 0.f, 0.f, 0.f};

    #pragma unroll 2
    for (int i = beg; i < end; i += 8) {
        int iA = i + es;       bool vA = iA < end;
        int iB = i + 4 + es;   bool vB = iB < end;
        int snA = srcs[vA ? iA : beg];
        int snB = srcs[vB ? iB : beg];
        f16x8 hA = *(const f16x8*)(xlh + (size_t)snA * F + q * 8);
        f16x8 hB = *(const f16x8*)(xlh + (size_t)snB * F + q * 8);
        const f16x2* a2 = (const f16x2*)&hA;
        const f16x2* b2 = (const f16x2*)&hB;

        f16x2 pA2 = {(_Float16)0.f, (_Float16)0.f};
        f16x2 pB2 = {(_Float16)0.f, (_Float16)0.f};
        #pragma unroll
        for (int j = 0; j < 4; ++j) {
            f16x2 eA = a2[j] + xrh[j];
            eA = __builtin_elementwise_max(eA, eA * slope);   // leaky_relu .2
            pA2 += eA * ath[j];
            f16x2 eB = b2[j] + xrh[j];
            eB = __builtin_elementwise_max(eB, eB * slope);
            pB2 += eB * ath[j];
        }
        float pA = (float)pA2[0] + (float)pA2[1];
        float pB = (float)pB2[0] + (float)pB2[1];
        pA += __shfl_xor(pA, 1); pA += __shfl_xor(pA, 2);     // head quad reduce
        pB += __shfl_xor(pB, 1); pB += __shfl_xor(pB, 2);
        float wA = vA ? __expf(pA) : 0.f;
        float wB = vB ? __expf(pB) : 0.f;
        s += wA + wB;
        #pragma unroll
        for (int j = 0; j < 8; ++j) {
            o[j] = fmaf(wA, (float)hA[j], o[j]);
            o[j] = fmaf(wB, (float)hB[j], o[j]);
        }
    }

    s += __shfl_xor(s, 16); s += __shfl_xor(s, 32);
    #pragma unroll
    for (int j = 0; j < 8; ++j) {
        o[j] += __shfl_xor(o[j], 16);
        o[j] += __shfl_xor(o[j], 32);
    }

    if (es == 0) {
        float inv = 1.f / (s + 1e-16f);
        float r[8];
        #pragma unroll
        for (int j = 0; j < 8; ++j) {
            r[j] = fmaf(o[j], inv, bias[q * 8 + j]);
            if (do_relu) r[j] = fmaxf(r[j], 0.f);
        }
        if (out_half) {
            f16x8 hv;
            #pragma unroll
            for (int j = 0; j < 8; ++j) hv[j] = (_Float16)r[j];
            *(f16x8*)(outh + (size_t)node * F + q * 8) = hv;
        } else {
            float4 lo = {r[0], r[1], r[2], r[3]};
            float4 hi = {r[4], r[5], r[6], r[7]};
            *(float4*)(outf + (size_t)node * F + q * 8) = lo;
            *(float4*)(outf + (size_t)node * F + q * 8 + 4) = hi;
        }
    }
}

// ---------------- launch ----------------

extern "C" void kernel_launch(void* const* d_in, const int* in_sizes, int n_in,
                              void* d_out, int out_size, void* d_ws, size_t ws_size,
                              hipStream_t stream)
{
    const float* x    = (const float*)d_in[0];
    const int*   ei   = (const int*)d_in[1];
    const float* Wl1  = (const float*)d_in[2];
    const float* Wr1  = (const float*)d_in[3];
    const float* Wl2  = (const float*)d_in[4];
    const float* Wr2  = (const float*)d_in[5];
    const float* bl1  = (const float*)d_in[6];
    const float* br1  = (const float*)d_in[7];
    const float* bl2  = (const float*)d_in[8];
    const float* br2  = (const float*)d_in[9];
    const float* att1 = (const float*)d_in[10];
    const float* att2 = (const float*)d_in[11];
    const float* b1   = (const float*)d_in[12];
    const float* b2   = (const float*)d_in[13];

    const int N = in_sizes[0] / F;
    const int E = in_sizes[1] / 2;
    const int* src = ei;
    const int* dst = ei + E;

    char* ws = (char*)d_ws;
    size_t off = 0;
    auto alloc = [&](size_t bytes) -> void* {
        void* p = ws + off;
        off = (off + bytes + 255) & ~(size_t)255;
        return p;
    };
    _Float16* hh   = (_Float16*)alloc((size_t)N * F * sizeof(_Float16));  // fp16 h (layer2 in)
    _Float16* xlh  = (_Float16*)alloc((size_t)N * F * sizeof(_Float16));  // fp16 xl
    float*    xr   = (float*)alloc((size_t)N * F * sizeof(float));        // fp32 xr
    _Float16* Wt1l = (_Float16*)alloc((size_t)F * F * sizeof(_Float16));
    _Float16* Wt1r = (_Float16*)alloc((size_t)F * F * sizeof(_Float16));
    _Float16* Wt2l = (_Float16*)alloc((size_t)F * F * sizeof(_Float16));
    _Float16* Wt2r = (_Float16*)alloc((size_t)F * F * sizeof(_Float16));
    int*   row_ptr = (int*)alloc((size_t)(N + 1) * sizeof(int));
    int*   counts  = (int*)alloc((size_t)NB * G * sizeof(int));
    int*   offsets = (int*)alloc((size_t)NB * G * sizeof(int));
    uint2* pairs   = (uint2*)alloc((size_t)E * sizeof(uint2));
    int*   srcs    = (int*)alloc((size_t)E * sizeof(int));

    // bucketed CSR build + weight convert (4 dispatches)
    const int chunk = (E + G - 1) / G;
    hist_convw_kernel<<<G + 64, 1024, 0, stream>>>(dst, counts, E, chunk,
                                                   Wl1, Wr1, Wl2, Wr2,
                                                   Wt1l, Wt1r, Wt2l, Wt2r);
    scan_fused_kernel<<<1, 1024, 0, stream>>>(counts, offsets);
    bucket_scatter_kernel<<<G, 1024, 0, stream>>>(src, dst, offsets, pairs, E, chunk);
    bucket_csr_kernel<<<NB, 256, 0, stream>>>(pairs, offsets, row_ptr, srcs, N, E);

    const int gemm_blocks = (N + 63) / 64;
    dim3 gemm_grid(gemm_blocks, 2);
    dim3 eb(64, 4);
    const int edge_blocks = (N + 3) / 4;

    // layer 1 (A fp32, converted inline)
    mfma_gemm_kernel<1><<<gemm_grid, 256, 0, stream>>>(
        x, Wt1l, bl1, Wt1r, br1, xlh, xr, N);
    gat_edge_kernel<<<edge_blocks, eb, 0, stream>>>(
        xlh, xr, srcs, row_ptr, att1, b1, nullptr, hh, N, 1, 1);

    // layer 2 (A fp16 from edge layer 1)
    mfma_gemm_kernel<0><<<gemm_grid, 256, 0, stream>>>(
        hh, Wt2l, bl2, Wt2r, br2, xlh, xr, N);
    gat_edge_kernel<<<edge_blocks, eb, 0, stream>>>(
        xlh, xr, srcs, row_ptr, att2, b2, (float*)d_out, nullptr, N, 0, 0);
}

// Round 14
// 157.946 us; speedup vs baseline: 2.4356x; 1.0609x over previous
//
#include <hip/hip_runtime.h>
#include <hip/hip_bf16.h>
#include <hip/hip_fp16.h>
#include <float.h>

#define F 128          // hidden = H*C
#define HEADS 4
#define CPH 32

// bucket sort params: bucket = dst>>7 (N=50000 <= 65536), 512 buckets,
// G=64 edge-chunk blocks -> counts matrix 512x64 = 32768.
#define NB 512
#define BSHIFT 7
#define G 64

using f16x2 = __attribute__((ext_vector_type(2))) _Float16;
using f16x8 = __attribute__((ext_vector_type(8))) _Float16;
using f32x4 = __attribute__((ext_vector_type(4))) float;

// ---------------- fused bucket-hist + weight/att convert ----------------
// blocks 0..G-1: per-block bucket histogram of dst>>7.
// blocks G..G+63: W[k][n] fp32 -> Wt[n][k] fp16 (4 matrices x 16 chunks).
// block G+64: att1/att2 fp32 -> fp16.

__global__ __launch_bounds__(1024) void hist_convw_kernel(
    const int* __restrict__ dst, int* __restrict__ counts, int E, int chunk,
    const float* __restrict__ W0, const float* __restrict__ W1,
    const float* __restrict__ W2, const float* __restrict__ W3,
    _Float16* __restrict__ T0, _Float16* __restrict__ T1,
    _Float16* __restrict__ T2, _Float16* __restrict__ T3,
    const float* __restrict__ att1, const float* __restrict__ att2,
    _Float16* __restrict__ attH1, _Float16* __restrict__ attH2)
{
    __shared__ int hist[NB];
    if (blockIdx.x < G) {
        int blk = blockIdx.x;
        for (int b = threadIdx.x; b < NB; b += 1024) hist[b] = 0;
        __syncthreads();
        int e0 = blk * chunk, e1 = min(e0 + chunk, E);
        for (int e = e0 + threadIdx.x; e < e1; e += 1024)
            atomicAdd(&hist[dst[e] >> BSHIFT], 1);
        __syncthreads();
        for (int b = threadIdx.x; b < NB; b += 1024)
            counts[b * G + blk] = hist[b];
    } else if (blockIdx.x < G + 64) {
        int b = blockIdx.x - G;                       // 0..63
        int m = b >> 4;
        int tid = (b & 15) * 1024 + threadIdx.x;      // 0..16383 = n*128+k
        int n = tid >> 7, k = tid & 127;
        const float* W = m == 0 ? W0 : m == 1 ? W1 : m == 2 ? W2 : W3;
        _Float16*    T = m == 0 ? T0 : m == 1 ? T1 : m == 2 ? T2 : T3;
        T[tid] = (_Float16)W[k * F + n];
    } else {
        if (threadIdx.x < 128)      attH1[threadIdx.x] = (_Float16)att1[threadIdx.x];
        else if (threadIdx.x < 256) attH2[threadIdx.x - 128] = (_Float16)att2[threadIdx.x - 128];
    }
}

// ---------------- fused single-block scan of counts (32768 = 1024 x 32) ----------------

__global__ __launch_bounds__(1024) void scan_fused_kernel(
    const int* __restrict__ counts, int* __restrict__ offsets)
{
    __shared__ int tmp[1024];
    int t = threadIdx.x;
    int loc[32];
    int s = 0;
    #pragma unroll
    for (int j = 0; j < 32; ++j) { loc[j] = s; s += counts[t * 32 + j]; }
    tmp[t] = s;
    __syncthreads();
    for (int o = 1; o < 1024; o <<= 1) {
        int a = (t >= o) ? tmp[t - o] : 0;
        __syncthreads();
        tmp[t] += a;
        __syncthreads();
    }
    int excl = tmp[t] - s;
    #pragma unroll
    for (int j = 0; j < 32; ++j) offsets[t * 32 + j] = excl + loc[j];
}

// pass C: scatter (src,dst) pairs into bucket-sorted order via LDS cursors
__global__ __launch_bounds__(1024) void bucket_scatter_kernel(
    const int* __restrict__ src, const int* __restrict__ dst,
    const int* __restrict__ offsets, uint2* __restrict__ pairs, int E, int chunk)
{
    __shared__ int curs[NB];
    int blk = blockIdx.x;
    for (int b = threadIdx.x; b < NB; b += 1024) curs[b] = offsets[b * G + blk];
    __syncthreads();
    int e0 = blk * chunk, e1 = min(e0 + chunk, E);
    for (int e = e0 + threadIdx.x; e < e1; e += 1024) {
        int d = dst[e];
        int pos = atomicAdd(&curs[d >> BSHIFT], 1);
        pairs[pos] = make_uint2((unsigned)src[e], (unsigned)d);
    }
}

// pass D: per-bucket local hist + scan -> row_ptr AND final srcs (block-private
// segment). srcs stores BYTE offsets (src*256 = src row in fp16) to kill the
// per-gather 64-bit address mul in the edge kernel.
__global__ __launch_bounds__(256) void bucket_csr_kernel(
    const uint2* __restrict__ pairs, const int* __restrict__ offsets,
    int* __restrict__ row_ptr, int* __restrict__ srcs8, int N, int E)
{
    int b = blockIdx.x;                    // 0..NB-1
    int seg0 = offsets[b * G];
    int seg1 = (b < NB - 1) ? offsets[(b + 1) * G] : E;
    __shared__ int hist[128], curs[128];
    if (threadIdx.x < 128) hist[threadIdx.x] = 0;
    __syncthreads();
    for (int e = seg0 + threadIdx.x; e < seg1; e += 256)
        atomicAdd(&hist[pairs[e].y & 127], 1);
    __syncthreads();
    int v = (threadIdx.x < 128) ? hist[threadIdx.x] : 0;
    if (threadIdx.x < 128) curs[threadIdx.x] = v;
    __syncthreads();
    for (int o = 1; o < 128; o <<= 1) {
        int a = 0;
        if (threadIdx.x < 128 && threadIdx.x >= o) a = curs[threadIdx.x - o];
        __syncthreads();
        if (threadIdx.x < 128) curs[threadIdx.x] += a;
        __syncthreads();
    }
    int excl = (threadIdx.x < 128) ? curs[threadIdx.x] - v : 0;
    __syncthreads();
    if (threadIdx.x < 128) {
        int node = b * 128 + threadIdx.x;
        if (node <= N) row_ptr[node] = seg0 + excl;
        curs[threadIdx.x] = excl;
    }
    __syncthreads();
    for (int e = seg0 + threadIdx.x; e < seg1; e += 256) {
        uint2 p = pairs[e];
        int pos = seg0 + atomicAdd(&curs[p.y & 127], 1);
        srcs8[pos] = (int)(p.x << 8);      // byte offset of fp16 row (128*2B)
    }
}

// ---------------- MFMA GEMM, LDS-staged B (R10-proven; both outputs fp16) -----------
// grid (nb, 2): blockIdx.y = matrix (0: Wl -> xl, 1: Wr -> xr), both fp16 out.
// 256 thr = 4 waves x 16 rows. W^T in LDS, 17-granule row pad.
// A/B share k-slot map (k = t*32+g*8+j); C/D: col=lane&15, row=(lane>>4)*4+reg.

template<int A_FP32>
__global__ __launch_bounds__(256) void mfma_gemm_kernel(
    const void* __restrict__ Xin,
    const _Float16* __restrict__ Wlt, const float* __restrict__ bl,
    const _Float16* __restrict__ Wrt, const float* __restrict__ br,
    _Float16* __restrict__ xl, _Float16* __restrict__ xr, int N)
{
    const int m = blockIdx.y;
    const _Float16* Wt = m ? Wrt : Wlt;

    __shared__ f16x8 Ws[F * 17];             // 128 rows x (16 data + 1 pad) granules
    for (int i = threadIdx.x; i < F * 16; i += 256) {
        int row = i >> 4, g = i & 15;
        Ws[row * 17 + g] = ((const f16x8*)Wt)[i];
    }
    __syncthreads();

    const int wid  = threadIdx.x >> 6;
    const int lane = threadIdx.x & 63;
    const int row0 = blockIdx.x * 64 + wid * 16;
    const int arow = lane & 15;
    const int g    = lane >> 4;              // 0..3

    int xrow = row0 + arow;
    if (xrow >= N) xrow = N - 1;             // clamp (C stores guarded)
    f16x8 af[4];
    if (A_FP32) {
        const float* xp = (const float*)Xin + (size_t)xrow * F + g * 8;
        #pragma unroll
        for (int t = 0; t < 4; ++t) {
            float4 lo = *(const float4*)(xp + t * 32);
            float4 hi = *(const float4*)(xp + t * 32 + 4);
            f16x8 a;
            a[0] = (_Float16)lo.x; a[1] = (_Float16)lo.y; a[2] = (_Float16)lo.z; a[3] = (_Float16)lo.w;
            a[4] = (_Float16)hi.x; a[5] = (_Float16)hi.y; a[6] = (_Float16)hi.z; a[7] = (_Float16)hi.w;
            af[t] = a;
        }
    } else {
        const _Float16* xp = (const _Float16*)Xin + (size_t)xrow * F + g * 8;
        #pragma unroll
        for (int t = 0; t < 4; ++t)
            af[t] = *(const f16x8*)(xp + t * 32);
    }

    f32x4 acc[8];
    #pragma unroll
    for (int nt = 0; nt < 8; ++nt) acc[nt] = (f32x4){0.f, 0.f, 0.f, 0.f};

    #pragma unroll
    for (int t = 0; t < 4; ++t)
        #pragma unroll
        for (int nt = 0; nt < 8; ++nt) {
            f16x8 b = Ws[(nt * 16 + arow) * 17 + (t * 4 + g)];
            acc[nt] = __builtin_amdgcn_mfma_f32_16x16x32_f16(af[t], b, acc[nt], 0, 0, 0);
        }

    const float* bias = m ? br : bl;
    _Float16* out = m ? xr : xl;
    #pragma unroll
    for (int nt = 0; nt < 8; ++nt) {
        int ccol = nt * 16 + (lane & 15);
        float bv = bias[ccol];
        #pragma unroll
        for (int r2 = 0; r2 < 4; ++r2) {
            int crow = row0 + (lane >> 4) * 4 + r2;
            if (crow < N)
                out[(size_t)crow * F + ccol] = (_Float16)(acc[nt][r2] + bv);
        }
    }
}

// ---------------- fused edge phase v4: 16-lane node groups ----------------
// 4 nodes/wave (16 lanes each), 16 nodes/block. Lane q = l&15 owns channels
// 8q..8q+7 EXCLUSIVELY -> o[] lane-local, s quad-redundant: NO epilogue
// cross-lane combine (v3 spent ~36 insts/node there). Head quad = 4 lanes ->
// 2-shfl logit reduce (stays inside the 16-lane group). 2 edges in flight per
// group. srcs8 holds byte offsets; xr/att are fp16 (1 b128 prologue load each).

__global__ __launch_bounds__(256) void gat_edge_kernel(
    const char* __restrict__ xlh_bytes, const _Float16* __restrict__ xrh,
    const int* __restrict__ srcs8, const int* __restrict__ row_ptr,
    const _Float16* __restrict__ attH, const float* __restrict__ bias,
    float* __restrict__ outf, _Float16* __restrict__ outh,
    int N, int do_relu, int out_half)
{
    int lane = threadIdx.x;      // 0..63
    int grp  = lane >> 4;        // node group 0..3
    int q    = lane & 15;        // channel-oct: channels 8q..8q+7
    int node = blockIdx.x * 16 + threadIdx.y * 4 + grp;
    if (node >= N) return;

    f16x8 xr8 = *(const f16x8*)(xrh + (size_t)node * F + q * 8);
    f16x8 at8 = *(const f16x8*)(attH + q * 8);
    const f16x2* xr2 = (const f16x2*)&xr8;
    const f16x2* at2 = (const f16x2*)&at8;
    const f16x2 slope = {(_Float16)0.2f, (_Float16)0.2f};

    int beg = row_ptr[node], end = row_ptr[node + 1];
    float s = 0.f;
    float o[8] = {0.f, 0.f, 0.f, 0.f, 0.f, 0.f, 0.f, 0.f};

    for (int i = beg; i < end; i += 2) {
        int offA = srcs8[i];
        bool vB = (i + 1) < end;
        int offB = srcs8[vB ? i + 1 : i];
        f16x8 hA = *(const f16x8*)(xlh_bytes + (size_t)(unsigned)offA + q * 16);
        f16x8 hB = *(const f16x8*)(xlh_bytes + (size_t)(unsigned)offB + q * 16);
        const f16x2* a2 = (const f16x2*)&hA;
        const f16x2* b2 = (const f16x2*)&hB;

        f16x2 pA2 = {(_Float16)0.f, (_Float16)0.f};
        f16x2 pB2 = {(_Float16)0.f, (_Float16)0.f};
        #pragma unroll
        for (int j = 0; j < 4; ++j) {
            f16x2 eA = a2[j] + xr2[j];
            eA = __builtin_elementwise_max(eA, eA * slope);   // leaky_relu .2
            pA2 += eA * at2[j];
            f16x2 eB = b2[j] + xr2[j];
            eB = __builtin_elementwise_max(eB, eB * slope);
            pB2 += eB * at2[j];
        }
        float pA = (float)pA2[0] + (float)pA2[1];
        float pB = (float)pB2[0] + (float)pB2[1];
        pA += __shfl_xor(pA, 1); pA += __shfl_xor(pA, 2);     // head quad reduce
        pB += __shfl_xor(pB, 1); pB += __shfl_xor(pB, 2);
        float wA = __expf(pA);
        float wB = vB ? __expf(pB) : 0.f;
        s += wA + wB;
        #pragma unroll
        for (int j = 0; j < 8; ++j) {
            o[j] = fmaf(wA, (float)hA[j], o[j]);
            o[j] = fmaf(wB, (float)hB[j], o[j]);
        }
    }

    float inv = 1.f / (s + 1e-16f);
    float r[8];
    #pragma unroll
    for (int j = 0; j < 8; ++j) {
        r[j] = fmaf(o[j], inv, bias[q * 8 + j]);
        if (do_relu) r[j] = fmaxf(r[j], 0.f);
    }
    if (out_half) {
        f16x8 hv;
        #pragma unroll
        for (int j = 0; j < 8; ++j) hv[j] = (_Float16)r[j];
        *(f16x8*)(outh + (size_t)node * F + q * 8) = hv;
    } else {
        float4 lo = {r[0], r[1], r[2], r[3]};
        float4 hi = {r[4], r[5], r[6], r[7]};
        *(float4*)(outf + (size_t)node * F + q * 8) = lo;
        *(float4*)(outf + (size_t)node * F + q * 8 + 4) = hi;
    }
}

// ---------------- launch ----------------

extern "C" void kernel_launch(void* const* d_in, const int* in_sizes, int n_in,
                              void* d_out, int out_size, void* d_ws, size_t ws_size,
                              hipStream_t stream)
{
    const float* x    = (const float*)d_in[0];
    const int*   ei   = (const int*)d_in[1];
    const float* Wl1  = (const float*)d_in[2];
    const float* Wr1  = (const float*)d_in[3];
    const float* Wl2  = (const float*)d_in[4];
    const float* Wr2  = (const float*)d_in[5];
    const float* bl1  = (const float*)d_in[6];
    const float* br1  = (const float*)d_in[7];
    const float* bl2  = (const float*)d_in[8];
    const float* br2  = (const float*)d_in[9];
    const float* att1 = (const float*)d_in[10];
    const float* att2 = (const float*)d_in[11];
    const float* b1   = (const float*)d_in[12];
    const float* b2   = (const float*)d_in[13];

    const int N = in_sizes[0] / F;
    const int E = in_sizes[1] / 2;
    const int* src = ei;
    const int* dst = ei + E;

    char* ws = (char*)d_ws;
    size_t off = 0;
    auto alloc = [&](size_t bytes) -> void* {
        void* p = ws + off;
        off = (off + bytes + 255) & ~(size_t)255;
        return p;
    };
    _Float16* hh   = (_Float16*)alloc((size_t)N * F * sizeof(_Float16));  // fp16 h (layer2 in)
    _Float16* xlh  = (_Float16*)alloc((size_t)N * F * sizeof(_Float16));  // fp16 xl
    _Float16* xrh  = (_Float16*)alloc((size_t)N * F * sizeof(_Float16));  // fp16 xr
    _Float16* Wt1l = (_Float16*)alloc((size_t)F * F * sizeof(_Float16));
    _Float16* Wt1r = (_Float16*)alloc((size_t)F * F * sizeof(_Float16));
    _Float16* Wt2l = (_Float16*)alloc((size_t)F * F * sizeof(_Float16));
    _Float16* Wt2r = (_Float16*)alloc((size_t)F * F * sizeof(_Float16));
    _Float16* attH1 = (_Float16*)alloc(F * sizeof(_Float16));
    _Float16* attH2 = (_Float16*)alloc(F * sizeof(_Float16));
    int*   row_ptr = (int*)alloc((size_t)(N + 1) * sizeof(int));
    int*   counts  = (int*)alloc((size_t)NB * G * sizeof(int));
    int*   offsets = (int*)alloc((size_t)NB * G * sizeof(int));
    uint2* pairs   = (uint2*)alloc((size_t)E * sizeof(uint2));
    int*   srcs8   = (int*)alloc((size_t)E * sizeof(int));

    // bucketed CSR build + weight/att convert (4 dispatches)
    const int chunk = (E + G - 1) / G;
    hist_convw_kernel<<<G + 65, 1024, 0, stream>>>(dst, counts, E, chunk,
                                                   Wl1, Wr1, Wl2, Wr2,
                                                   Wt1l, Wt1r, Wt2l, Wt2r,
                                                   att1, att2, attH1, attH2);
    scan_fused_kernel<<<1, 1024, 0, stream>>>(counts, offsets);
    bucket_scatter_kernel<<<G, 1024, 0, stream>>>(src, dst, offsets, pairs, E, chunk);
    bucket_csr_kernel<<<NB, 256, 0, stream>>>(pairs, offsets, row_ptr, srcs8, N, E);

    const int gemm_blocks = (N + 63) / 64;
    dim3 gemm_grid(gemm_blocks, 2);
    dim3 eb(64, 4);
    const int edge_blocks = (N + 15) / 16;

    // layer 1 (A fp32, converted inline)
    mfma_gemm_kernel<1><<<gemm_grid, 256, 0, stream>>>(
        x, Wt1l, bl1, Wt1r, br1, xlh, xrh, N);
    gat_edge_kernel<<<edge_blocks, eb, 0, stream>>>(
        (const char*)xlh, xrh, srcs8, row_ptr, attH1, b1,
        nullptr, hh, N, 1, 1);

    // layer 2 (A fp16 from edge layer 1)
    mfma_gemm_kernel<0><<<gemm_grid, 256, 0, stream>>>(
        hh, Wt2l, bl2, Wt2r, br2, xlh, xrh, N);
    gat_edge_kernel<<<edge_blocks, eb, 0, stream>>>(
        (const char*)xlh, xrh, srcs8, row_ptr, attH2, b2,
        (float*)d_out, nullptr, N, 0, 0);
}

// Round 15
// 155.629 us; speedup vs baseline: 2.4719x; 1.0149x over previous
//
#include <hip/hip_runtime.h>
#include <hip/hip_bf16.h>
#include <hip/hip_fp16.h>
#include <float.h>

#define F 128          // hidden = H*C
#define HEADS 4
#define CPH 32

// bucket sort params: bucket = dst>>7 (N=50000 <= 65536), 512 buckets,
// G=64 edge-chunk blocks -> counts matrix 512x64 = 32768.
#define NB 512
#define BSHIFT 7
#define G 64

using f16x2 = __attribute__((ext_vector_type(2))) _Float16;
using f16x8 = __attribute__((ext_vector_type(8))) _Float16;
using f32x4 = __attribute__((ext_vector_type(4))) float;

// ---------------- fused bucket-hist + weight/att convert ----------------

__global__ __launch_bounds__(1024) void hist_convw_kernel(
    const int* __restrict__ dst, int* __restrict__ counts, int E, int chunk,
    const float* __restrict__ W0, const float* __restrict__ W1,
    const float* __restrict__ W2, const float* __restrict__ W3,
    _Float16* __restrict__ T0, _Float16* __restrict__ T1,
    _Float16* __restrict__ T2, _Float16* __restrict__ T3,
    const float* __restrict__ att1, const float* __restrict__ att2,
    _Float16* __restrict__ attH1, _Float16* __restrict__ attH2)
{
    __shared__ int hist[NB];
    if (blockIdx.x < G) {
        int blk = blockIdx.x;
        for (int b = threadIdx.x; b < NB; b += 1024) hist[b] = 0;
        __syncthreads();
        int e0 = blk * chunk, e1 = min(e0 + chunk, E);
        for (int e = e0 + threadIdx.x; e < e1; e += 1024)
            atomicAdd(&hist[dst[e] >> BSHIFT], 1);
        __syncthreads();
        for (int b = threadIdx.x; b < NB; b += 1024)
            counts[b * G + blk] = hist[b];
    } else if (blockIdx.x < G + 64) {
        int b = blockIdx.x - G;                       // 0..63
        int m = b >> 4;
        int tid = (b & 15) * 1024 + threadIdx.x;      // 0..16383 = n*128+k
        int n = tid >> 7, k = tid & 127;
        const float* W = m == 0 ? W0 : m == 1 ? W1 : m == 2 ? W2 : W3;
        _Float16*    T = m == 0 ? T0 : m == 1 ? T1 : m == 2 ? T2 : T3;
        T[tid] = (_Float16)W[k * F + n];
    } else {
        if (threadIdx.x < 128)      attH1[threadIdx.x] = (_Float16)att1[threadIdx.x];
        else if (threadIdx.x < 256) attH2[threadIdx.x - 128] = (_Float16)att2[threadIdx.x - 128];
    }
}

// ---------------- fused single-block scan of counts (32768 = 1024 x 32) ----------------

__global__ __launch_bounds__(1024) void scan_fused_kernel(
    const int* __restrict__ counts, int* __restrict__ offsets)
{
    __shared__ int tmp[1024];
    int t = threadIdx.x;
    int loc[32];
    int s = 0;
    #pragma unroll
    for (int j = 0; j < 32; ++j) { loc[j] = s; s += counts[t * 32 + j]; }
    tmp[t] = s;
    __syncthreads();
    for (int o = 1; o < 1024; o <<= 1) {
        int a = (t >= o) ? tmp[t - o] : 0;
        __syncthreads();
        tmp[t] += a;
        __syncthreads();
    }
    int excl = tmp[t] - s;
    #pragma unroll
    for (int j = 0; j < 32; ++j) offsets[t * 32 + j] = excl + loc[j];
}

// pass C: scatter PACKED (src<<7)|(dst&127) into bucket-sorted order (4B/edge;
// src < 2^16 and bucket-local node id is 7 bits -> 23 bits total).
__global__ __launch_bounds__(1024) void bucket_scatter_kernel(
    const int* __restrict__ src, const int* __restrict__ dst,
    const int* __restrict__ offsets, unsigned* __restrict__ pairs, int E, int chunk)
{
    __shared__ int curs[NB];
    int blk = blockIdx.x;
    for (int b = threadIdx.x; b < NB; b += 1024) curs[b] = offsets[b * G + blk];
    __syncthreads();
    int e0 = blk * chunk, e1 = min(e0 + chunk, E);
    for (int e = e0 + threadIdx.x; e < e1; e += 1024) {
        int d = dst[e];
        int pos = atomicAdd(&curs[d >> BSHIFT], 1);
        pairs[pos] = ((unsigned)src[e] << 7) | (unsigned)(d & 127);
    }
}

// pass D: per-bucket local hist + scan -> row_ptr AND srcs8 (byte offsets, src*256).
__global__ __launch_bounds__(256) void bucket_csr_kernel(
    const unsigned* __restrict__ pairs, const int* __restrict__ offsets,
    int* __restrict__ row_ptr, int* __restrict__ srcs8, int N, int E)
{
    int b = blockIdx.x;                    // 0..NB-1
    int seg0 = offsets[b * G];
    int seg1 = (b < NB - 1) ? offsets[(b + 1) * G] : E;
    __shared__ int hist[128], curs[128];
    if (threadIdx.x < 128) hist[threadIdx.x] = 0;
    __syncthreads();
    for (int e = seg0 + threadIdx.x; e < seg1; e += 256)
        atomicAdd(&hist[pairs[e] & 127], 1);
    __syncthreads();
    int v = (threadIdx.x < 128) ? hist[threadIdx.x] : 0;
    if (threadIdx.x < 128) curs[threadIdx.x] = v;
    __syncthreads();
    for (int o = 1; o < 128; o <<= 1) {
        int a = 0;
        if (threadIdx.x < 128 && threadIdx.x >= o) a = curs[threadIdx.x - o];
        __syncthreads();
        if (threadIdx.x < 128) curs[threadIdx.x] += a;
        __syncthreads();
    }
    int excl = (threadIdx.x < 128) ? curs[threadIdx.x] - v : 0;
    __syncthreads();
    if (threadIdx.x < 128) {
        int node = b * 128 + threadIdx.x;
        if (node <= N) row_ptr[node] = seg0 + excl;
        curs[threadIdx.x] = excl;
    }
    __syncthreads();
    for (int e = seg0 + threadIdx.x; e < seg1; e += 256) {
        unsigned p = pairs[e];
        int pos = seg0 + atomicAdd(&curs[p & 127], 1);
        srcs8[pos] = (int)((p >> 7) << 8);   // byte offset of fp16 row (128*2B)
    }
}

// ---------------- MFMA GEMM, LDS-staged B (R10-proven; both outputs fp16) -----------

template<int A_FP32>
__global__ __launch_bounds__(256) void mfma_gemm_kernel(
    const void* __restrict__ Xin,
    const _Float16* __restrict__ Wlt, const float* __restrict__ bl,
    const _Float16* __restrict__ Wrt, const float* __restrict__ br,
    _Float16* __restrict__ xl, _Float16* __restrict__ xr, int N)
{
    const int m = blockIdx.y;
    const _Float16* Wt = m ? Wrt : Wlt;

    __shared__ f16x8 Ws[F * 17];             // 128 rows x (16 data + 1 pad) granules
    for (int i = threadIdx.x; i < F * 16; i += 256) {
        int row = i >> 4, g = i & 15;
        Ws[row * 17 + g] = ((const f16x8*)Wt)[i];
    }
    __syncthreads();

    const int wid  = threadIdx.x >> 6;
    const int lane = threadIdx.x & 63;
    const int row0 = blockIdx.x * 64 + wid * 16;
    const int arow = lane & 15;
    const int g    = lane >> 4;              // 0..3

    int xrow = row0 + arow;
    if (xrow >= N) xrow = N - 1;             // clamp (C stores guarded)
    f16x8 af[4];
    if (A_FP32) {
        const float* xp = (const float*)Xin + (size_t)xrow * F + g * 8;
        #pragma unroll
        for (int t = 0; t < 4; ++t) {
            float4 lo = *(const float4*)(xp + t * 32);
            float4 hi = *(const float4*)(xp + t * 32 + 4);
            f16x8 a;
            a[0] = (_Float16)lo.x; a[1] = (_Float16)lo.y; a[2] = (_Float16)lo.z; a[3] = (_Float16)lo.w;
            a[4] = (_Float16)hi.x; a[5] = (_Float16)hi.y; a[6] = (_Float16)hi.z; a[7] = (_Float16)hi.w;
            af[t] = a;
        }
    } else {
        const _Float16* xp = (const _Float16*)Xin + (size_t)xrow * F + g * 8;
        #pragma unroll
        for (int t = 0; t < 4; ++t)
            af[t] = *(const f16x8*)(xp + t * 32);
    }

    f32x4 acc[8];
    #pragma unroll
    for (int nt = 0; nt < 8; ++nt) acc[nt] = (f32x4){0.f, 0.f, 0.f, 0.f};

    #pragma unroll
    for (int t = 0; t < 4; ++t)
        #pragma unroll
        for (int nt = 0; nt < 8; ++nt) {
            f16x8 b = Ws[(nt * 16 + arow) * 17 + (t * 4 + g)];
            acc[nt] = __builtin_amdgcn_mfma_f32_16x16x32_f16(af[t], b, acc[nt], 0, 0, 0);
        }

    const float* bias = m ? br : bl;
    _Float16* out = m ? xr : xl;
    #pragma unroll
    for (int nt = 0; nt < 8; ++nt) {
        int ccol = nt * 16 + (lane & 15);
        float bv = bias[ccol];
        #pragma unroll
        for (int r2 = 0; r2 < 4; ++r2) {
            int crow = row0 + (lane >> 4) * 4 + r2;
            if (crow < N)
                out[(size_t)crow * F + ccol] = (_Float16)(acc[nt][r2] + bv);
        }
    }
}

// ---------------- fused edge phase v5: 16-lane node groups, 4 edges in flight -------
// 4 nodes/wave (16 lanes each). Lane q = l&15 owns channels 8q..8q+7 exclusively
// -> o[] lane-local, no epilogue combine. Head quad = 4 lanes -> 2-shfl reduce.
// v4 was latency-bound (2 gathers in flight/group, beyond-L2 at 2.8 of ~6 TB/s);
// v5 keeps 4 gathers outstanding (unrolled A..D with masks).

__global__ __launch_bounds__(256) void gat_edge_kernel(
    const char* __restrict__ xlh_bytes, const _Float16* __restrict__ xrh,
    const int* __restrict__ srcs8, const int* __restrict__ row_ptr,
    const _Float16* __restrict__ attH, const float* __restrict__ bias,
    float* __restrict__ outf, _Float16* __restrict__ outh,
    int N, int do_relu, int out_half)
{
    int lane = threadIdx.x;      // 0..63
    int grp  = lane >> 4;        // node group 0..3
    int q    = lane & 15;        // channel-oct: channels 8q..8q+7
    int node = blockIdx.x * 16 + threadIdx.y * 4 + grp;
    if (node >= N) return;

    f16x8 xr8 = *(const f16x8*)(xrh + (size_t)node * F + q * 8);
    f16x8 at8 = *(const f16x8*)(attH + q * 8);
    const f16x2* xr2 = (const f16x2*)&xr8;
    const f16x2* at2 = (const f16x2*)&at8;
    const f16x2 slope = {(_Float16)0.2f, (_Float16)0.2f};

    int beg = row_ptr[node], end = row_ptr[node + 1];
    float s = 0.f;
    float o[8] = {0.f, 0.f, 0.f, 0.f, 0.f, 0.f, 0.f, 0.f};

    for (int i = beg; i < end; i += 4) {
        bool vB = (i + 1) < end, vC = (i + 2) < end, vD = (i + 3) < end;
        int offA = srcs8[i];
        int offB = srcs8[vB ? i + 1 : i];
        int offC = srcs8[vC ? i + 2 : i];
        int offD = srcs8[vD ? i + 3 : i];
        f16x8 hA = *(const f16x8*)(xlh_bytes + (size_t)(unsigned)offA + q * 16);
        f16x8 hB = *(const f16x8*)(xlh_bytes + (size_t)(unsigned)offB + q * 16);
        f16x8 hC = *(const f16x8*)(xlh_bytes + (size_t)(unsigned)offC + q * 16);
        f16x8 hD = *(const f16x8*)(xlh_bytes + (size_t)(unsigned)offD + q * 16);
        const f16x2* a2 = (const f16x2*)&hA;
        const f16x2* b2 = (const f16x2*)&hB;
        const f16x2* c2 = (const f16x2*)&hC;
        const f16x2* d2 = (const f16x2*)&hD;

        f16x2 pA2 = {(_Float16)0.f, (_Float16)0.f};
        f16x2 pB2 = pA2, pC2 = pA2, pD2 = pA2;
        #pragma unroll
        for (int j = 0; j < 4; ++j) {
            f16x2 eA = a2[j] + xr2[j];
            eA = __builtin_elementwise_max(eA, eA * slope);
            pA2 += eA * at2[j];
            f16x2 eB = b2[j] + xr2[j];
            eB = __builtin_elementwise_max(eB, eB * slope);
            pB2 += eB * at2[j];
            f16x2 eC = c2[j] + xr2[j];
            eC = __builtin_elementwise_max(eC, eC * slope);
            pC2 += eC * at2[j];
            f16x2 eD = d2[j] + xr2[j];
            eD = __builtin_elementwise_max(eD, eD * slope);
            pD2 += eD * at2[j];
        }
        float pA = (float)pA2[0] + (float)pA2[1];
        float pB = (float)pB2[0] + (float)pB2[1];
        float pC = (float)pC2[0] + (float)pC2[1];
        float pD = (float)pD2[0] + (float)pD2[1];
        pA += __shfl_xor(pA, 1); pA += __shfl_xor(pA, 2);
        pB += __shfl_xor(pB, 1); pB += __shfl_xor(pB, 2);
        pC += __shfl_xor(pC, 1); pC += __shfl_xor(pC, 2);
        pD += __shfl_xor(pD, 1); pD += __shfl_xor(pD, 2);
        float wA = __expf(pA);
        float wB = vB ? __expf(pB) : 0.f;
        float wC = vC ? __expf(pC) : 0.f;
        float wD = vD ? __expf(pD) : 0.f;
        s += (wA + wB) + (wC + wD);
        #pragma unroll
        for (int j = 0; j < 8; ++j) {
            o[j] = fmaf(wA, (float)hA[j], o[j]);
            o[j] = fmaf(wB, (float)hB[j], o[j]);
            o[j] = fmaf(wC, (float)hC[j], o[j]);
            o[j] = fmaf(wD, (float)hD[j], o[j]);
        }
    }

    float inv = 1.f / (s + 1e-16f);
    float r[8];
    #pragma unroll
    for (int j = 0; j < 8; ++j) {
        r[j] = fmaf(o[j], inv, bias[q * 8 + j]);
        if (do_relu) r[j] = fmaxf(r[j], 0.f);
    }
    if (out_half) {
        f16x8 hv;
        #pragma unroll
        for (int j = 0; j < 8; ++j) hv[j] = (_Float16)r[j];
        *(f16x8*)(outh + (size_t)node * F + q * 8) = hv;
    } else {
        float4 lo = {r[0], r[1], r[2], r[3]};
        float4 hi = {r[4], r[5], r[6], r[7]};
        *(float4*)(outf + (size_t)node * F + q * 8) = lo;
        *(float4*)(outf + (size_t)node * F + q * 8 + 4) = hi;
    }
}

// ---------------- launch ----------------

extern "C" void kernel_launch(void* const* d_in, const int* in_sizes, int n_in,
                              void* d_out, int out_size, void* d_ws, size_t ws_size,
                              hipStream_t stream)
{
    const float* x    = (const float*)d_in[0];
    const int*   ei   = (const int*)d_in[1];
    const float* Wl1  = (const float*)d_in[2];
    const float* Wr1  = (const float*)d_in[3];
    const float* Wl2  = (const float*)d_in[4];
    const float* Wr2  = (const float*)d_in[5];
    const float* bl1  = (const float*)d_in[6];
    const float* br1  = (const float*)d_in[7];
    const float* bl2  = (const float*)d_in[8];
    const float* br2  = (const float*)d_in[9];
    const float* att1 = (const float*)d_in[10];
    const float* att2 = (const float*)d_in[11];
    const float* b1   = (const float*)d_in[12];
    const float* b2   = (const float*)d_in[13];

    const int N = in_sizes[0] / F;
    const int E = in_sizes[1] / 2;
    const int* src = ei;
    const int* dst = ei + E;

    char* ws = (char*)d_ws;
    size_t off = 0;
    auto alloc = [&](size_t bytes) -> void* {
        void* p = ws + off;
        off = (off + bytes + 255) & ~(size_t)255;
        return p;
    };
    _Float16* hh   = (_Float16*)alloc((size_t)N * F * sizeof(_Float16));
    _Float16* xlh  = (_Float16*)alloc((size_t)N * F * sizeof(_Float16));
    _Float16* xrh  = (_Float16*)alloc((size_t)N * F * sizeof(_Float16));
    _Float16* Wt1l = (_Float16*)alloc((size_t)F * F * sizeof(_Float16));
    _Float16* Wt1r = (_Float16*)alloc((size_t)F * F * sizeof(_Float16));
    _Float16* Wt2l = (_Float16*)alloc((size_t)F * F * sizeof(_Float16));
    _Float16* Wt2r = (_Float16*)alloc((size_t)F * F * sizeof(_Float16));
    _Float16* attH1 = (_Float16*)alloc(F * sizeof(_Float16));
    _Float16* attH2 = (_Float16*)alloc(F * sizeof(_Float16));
    int*      row_ptr = (int*)alloc((size_t)(N + 1) * sizeof(int));
    int*      counts  = (int*)alloc((size_t)NB * G * sizeof(int));
    int*      offsets = (int*)alloc((size_t)NB * G * sizeof(int));
    unsigned* pairs   = (unsigned*)alloc((size_t)E * sizeof(unsigned));
    int*      srcs8   = (int*)alloc((size_t)E * sizeof(int));

    // bucketed CSR build + weight/att convert (4 dispatches)
    const int chunk = (E + G - 1) / G;
    hist_convw_kernel<<<G + 65, 1024, 0, stream>>>(dst, counts, E, chunk,
                                                   Wl1, Wr1, Wl2, Wr2,
                                                   Wt1l, Wt1r, Wt2l, Wt2r,
                                                   att1, att2, attH1, attH2);
    scan_fused_kernel<<<1, 1024, 0, stream>>>(counts, offsets);
    bucket_scatter_kernel<<<G, 1024, 0, stream>>>(src, dst, offsets, pairs, E, chunk);
    bucket_csr_kernel<<<NB, 256, 0, stream>>>(pairs, offsets, row_ptr, srcs8, N, E);

    const int gemm_blocks = (N + 63) / 64;
    dim3 gemm_grid(gemm_blocks, 2);
    dim3 eb(64, 4);
    const int edge_blocks = (N + 15) / 16;

    // layer 1 (A fp32, converted inline)
    mfma_gemm_kernel<1><<<gemm_grid, 256, 0, stream>>>(
        x, Wt1l, bl1, Wt1r, br1, xlh, xrh, N);
    gat_edge_kernel<<<edge_blocks, eb, 0, stream>>>(
        (const char*)xlh, xrh, srcs8, row_ptr, attH1, b1,
        nullptr, hh, N, 1, 1);

    // layer 2 (A fp16 from edge layer 1)
    mfma_gemm_kernel<0><<<gemm_grid, 256, 0, stream>>>(
        hh, Wt2l, bl2, Wt2r, br2, xlh, xrh, N);
    gat_edge_kernel<<<edge_blocks, eb, 0, stream>>>(
        (const char*)xlh, xrh, srcs8, row_ptr, attH2, b2,
        (float*)d_out, nullptr, N, 0, 0);
}

// Round 16
// 150.212 us; speedup vs baseline: 2.5610x; 1.0361x over previous
//
#include <hip/hip_runtime.h>
#include <hip/hip_bf16.h>
#include <hip/hip_fp16.h>
#include <float.h>

#define F 128          // hidden = H*C
#define HEADS 4
#define CPH 32

// bucket sort params: bucket = dst>>7 (N=50000 <= 65536), 512 buckets,
// G=64 edge-chunk blocks -> counts matrix 512x64 = 32768.
#define NB 512
#define BSHIFT 7
#define G 64
#define SEGCAP 5120    // LDS staging cap for a bucket segment (mean 1562, P(>5120)~0)

using f16x2 = __attribute__((ext_vector_type(2))) _Float16;
using f16x8 = __attribute__((ext_vector_type(8))) _Float16;
using f32x4 = __attribute__((ext_vector_type(4))) float;

// ---------------- fused bucket-hist + weight/att convert ----------------

__global__ __launch_bounds__(1024) void hist_convw_kernel(
    const int* __restrict__ dst, int* __restrict__ counts, int E, int chunk,
    const float* __restrict__ W0, const float* __restrict__ W1,
    const float* __restrict__ W2, const float* __restrict__ W3,
    _Float16* __restrict__ T0, _Float16* __restrict__ T1,
    _Float16* __restrict__ T2, _Float16* __restrict__ T3,
    const float* __restrict__ att1, const float* __restrict__ att2,
    _Float16* __restrict__ attH1, _Float16* __restrict__ attH2)
{
    __shared__ int hist[NB];
    if (blockIdx.x < G) {
        int blk = blockIdx.x;
        for (int b = threadIdx.x; b < NB; b += 1024) hist[b] = 0;
        __syncthreads();
        int e0 = blk * chunk, e1 = min(e0 + chunk, E);
        for (int e = e0 + threadIdx.x; e < e1; e += 1024)
            atomicAdd(&hist[dst[e] >> BSHIFT], 1);
        __syncthreads();
        for (int b = threadIdx.x; b < NB; b += 1024)
            counts[b * G + blk] = hist[b];
    } else if (blockIdx.x < G + 64) {
        int b = blockIdx.x - G;                       // 0..63
        int m = b >> 4;
        int tid = (b & 15) * 1024 + threadIdx.x;      // 0..16383 = n*128+k
        int n = tid >> 7, k = tid & 127;
        const float* W = m == 0 ? W0 : m == 1 ? W1 : m == 2 ? W2 : W3;
        _Float16*    T = m == 0 ? T0 : m == 1 ? T1 : m == 2 ? T2 : T3;
        T[tid] = (_Float16)W[k * F + n];
    } else {
        if (threadIdx.x < 128)      attH1[threadIdx.x] = (_Float16)att1[threadIdx.x];
        else if (threadIdx.x < 256) attH2[threadIdx.x - 128] = (_Float16)att2[threadIdx.x - 128];
    }
}

// ---------------- fused single-block scan of counts (32768 = 1024 x 32) ----------------

__global__ __launch_bounds__(1024) void scan_fused_kernel(
    const int* __restrict__ counts, int* __restrict__ offsets)
{
    __shared__ int tmp[1024];
    int t = threadIdx.x;
    int loc[32];
    int s = 0;
    #pragma unroll
    for (int j = 0; j < 32; ++j) { loc[j] = s; s += counts[t * 32 + j]; }
    tmp[t] = s;
    __syncthreads();
    for (int o = 1; o < 1024; o <<= 1) {
        int a = (t >= o) ? tmp[t - o] : 0;
        __syncthreads();
        tmp[t] += a;
        __syncthreads();
    }
    int excl = tmp[t] - s;
    #pragma unroll
    for (int j = 0; j < 32; ++j) offsets[t * 32 + j] = excl + loc[j];
}

// pass C: scatter PACKED (src<<7)|(dst&127) into bucket-sorted order (4B/edge)
__global__ __launch_bounds__(1024) void bucket_scatter_kernel(
    const int* __restrict__ src, const int* __restrict__ dst,
    const int* __restrict__ offsets, unsigned* __restrict__ pairs, int E, int chunk)
{
    __shared__ int curs[NB];
    int blk = blockIdx.x;
    for (int b = threadIdx.x; b < NB; b += 1024) curs[b] = offsets[b * G + blk];
    __syncthreads();
    int e0 = blk * chunk, e1 = min(e0 + chunk, E);
    for (int e = e0 + threadIdx.x; e < e1; e += 1024) {
        int d = dst[e];
        int pos = atomicAdd(&curs[d >> BSHIFT], 1);
        pairs[pos] = ((unsigned)src[e] << 7) | (unsigned)(d & 127);
    }
}

// pass D: per-bucket local hist + scan -> row_ptr AND srcs8 (byte offsets).
// Segment staged in LDS (one global pairs read instead of two).
__global__ __launch_bounds__(256) void bucket_csr_kernel(
    const unsigned* __restrict__ pairs, const int* __restrict__ offsets,
    int* __restrict__ row_ptr, int* __restrict__ srcs8, int N, int E)
{
    int b = blockIdx.x;                    // 0..NB-1
    int seg0 = offsets[b * G];
    int seg1 = (b < NB - 1) ? offsets[(b + 1) * G] : E;
    int len = seg1 - seg0;
    __shared__ int hist[128], curs[128];
    __shared__ unsigned seg[SEGCAP];
    bool fits = len <= SEGCAP;

    if (threadIdx.x < 128) hist[threadIdx.x] = 0;
    __syncthreads();
    if (fits) {
        for (int e = threadIdx.x; e < len; e += 256) {
            unsigned p = pairs[seg0 + e];
            seg[e] = p;
            atomicAdd(&hist[p & 127], 1);
        }
    } else {
        for (int e = seg0 + threadIdx.x; e < seg1; e += 256)
            atomicAdd(&hist[pairs[e] & 127], 1);
    }
    __syncthreads();
    int v = (threadIdx.x < 128) ? hist[threadIdx.x] : 0;
    if (threadIdx.x < 128) curs[threadIdx.x] = v;
    __syncthreads();
    for (int o = 1; o < 128; o <<= 1) {
        int a = 0;
        if (threadIdx.x < 128 && threadIdx.x >= o) a = curs[threadIdx.x - o];
        __syncthreads();
        if (threadIdx.x < 128) curs[threadIdx.x] += a;
        __syncthreads();
    }
    int excl = (threadIdx.x < 128) ? curs[threadIdx.x] - v : 0;
    __syncthreads();
    if (threadIdx.x < 128) {
        int node = b * 128 + threadIdx.x;
        if (node <= N) row_ptr[node] = seg0 + excl;
        curs[threadIdx.x] = excl;
    }
    __syncthreads();
    if (fits) {
        for (int e = threadIdx.x; e < len; e += 256) {
            unsigned p = seg[e];
            int pos = seg0 + atomicAdd(&curs[p & 127], 1);
            srcs8[pos] = (int)((p >> 7) << 8);
        }
    } else {
        for (int e = seg0 + threadIdx.x; e < seg1; e += 256) {
            unsigned p = pairs[e];
            int pos = seg0 + atomicAdd(&curs[p & 127], 1);
            srcs8[pos] = (int)((p >> 7) << 8);
        }
    }
}

// ---------------- MFMA GEMM, LDS-staged B; 512 thr, 128 rows/block ----------------
// grid (nb, 2): blockIdx.y = matrix (0: Wl -> xl, 1: Wr -> xr), both fp16 out.
// 8 waves x 16 rows = 128 rows/block: one W-stage amortized over 2x rows vs R10
// (W L2 traffic halved). W^T in LDS with 17-granule row pad.
// A/B share k-slot map (k = t*32+g*8+j); C/D: col=lane&15, row=(lane>>4)*4+reg.

template<int A_FP32>
__global__ __launch_bounds__(512) void mfma_gemm_kernel(
    const void* __restrict__ Xin,
    const _Float16* __restrict__ Wlt, const float* __restrict__ bl,
    const _Float16* __restrict__ Wrt, const float* __restrict__ br,
    _Float16* __restrict__ xl, _Float16* __restrict__ xr, int N)
{
    const int m = blockIdx.y;
    const _Float16* Wt = m ? Wrt : Wlt;

    __shared__ f16x8 Ws[F * 17];             // 128 rows x (16 data + 1 pad) granules
    for (int i = threadIdx.x; i < F * 16; i += 512) {
        int row = i >> 4, g = i & 15;
        Ws[row * 17 + g] = ((const f16x8*)Wt)[i];
    }
    __syncthreads();

    const int wid  = threadIdx.x >> 6;       // 0..7
    const int lane = threadIdx.x & 63;
    const int row0 = blockIdx.x * 128 + wid * 16;
    const int arow = lane & 15;
    const int g    = lane >> 4;              // 0..3

    int xrow = row0 + arow;
    if (xrow >= N) xrow = N - 1;             // clamp (C stores guarded)
    f16x8 af[4];
    if (A_FP32) {
        const float* xp = (const float*)Xin + (size_t)xrow * F + g * 8;
        #pragma unroll
        for (int t = 0; t < 4; ++t) {
            float4 lo = *(const float4*)(xp + t * 32);
            float4 hi = *(const float4*)(xp + t * 32 + 4);
            f16x8 a;
            a[0] = (_Float16)lo.x; a[1] = (_Float16)lo.y; a[2] = (_Float16)lo.z; a[3] = (_Float16)lo.w;
            a[4] = (_Float16)hi.x; a[5] = (_Float16)hi.y; a[6] = (_Float16)hi.z; a[7] = (_Float16)hi.w;
            af[t] = a;
        }
    } else {
        const _Float16* xp = (const _Float16*)Xin + (size_t)xrow * F + g * 8;
        #pragma unroll
        for (int t = 0; t < 4; ++t)
            af[t] = *(const f16x8*)(xp + t * 32);
    }

    f32x4 acc[8];
    #pragma unroll
    for (int nt = 0; nt < 8; ++nt) acc[nt] = (f32x4){0.f, 0.f, 0.f, 0.f};

    #pragma unroll
    for (int t = 0; t < 4; ++t)
        #pragma unroll
        for (int nt = 0; nt < 8; ++nt) {
            f16x8 b = Ws[(nt * 16 + arow) * 17 + (t * 4 + g)];
            acc[nt] = __builtin_amdgcn_mfma_f32_16x16x32_f16(af[t], b, acc[nt], 0, 0, 0);
        }

    const float* bias = m ? br : bl;
    _Float16* out = m ? xr : xl;
    #pragma unroll
    for (int nt = 0; nt < 8; ++nt) {
        int ccol = nt * 16 + (lane & 15);
        float bv = bias[ccol];
        #pragma unroll
        for (int r2 = 0; r2 < 4; ++r2) {
            int crow = row0 + (lane >> 4) * 4 + r2;
            if (crow < N)
                out[(size_t)crow * F + ccol] = (_Float16)(acc[nt][r2] + bv);
        }
    }
}

// ---------------- fused edge phase v5 (R15-proven): 16-lane groups, 4 in flight -----

__global__ __launch_bounds__(256) void gat_edge_kernel(
    const char* __restrict__ xlh_bytes, const _Float16* __restrict__ xrh,
    const int* __restrict__ srcs8, const int* __restrict__ row_ptr,
    const _Float16* __restrict__ attH, const float* __restrict__ bias,
    float* __restrict__ outf, _Float16* __restrict__ outh,
    int N, int do_relu, int out_half)
{
    int lane = threadIdx.x;      // 0..63
    int grp  = lane >> 4;        // node group 0..3
    int q    = lane & 15;        // channel-oct: channels 8q..8q+7
    int node = blockIdx.x * 16 + threadIdx.y * 4 + grp;
    if (node >= N) return;

    f16x8 xr8 = *(const f16x8*)(xrh + (size_t)node * F + q * 8);
    f16x8 at8 = *(const f16x8*)(attH + q * 8);
    const f16x2* xr2 = (const f16x2*)&xr8;
    const f16x2* at2 = (const f16x2*)&at8;
    const f16x2 slope = {(_Float16)0.2f, (_Float16)0.2f};

    int beg = row_ptr[node], end = row_ptr[node + 1];
    float s = 0.f;
    float o[8] = {0.f, 0.f, 0.f, 0.f, 0.f, 0.f, 0.f, 0.f};

    for (int i = beg; i < end; i += 4) {
        bool vB = (i + 1) < end, vC = (i + 2) < end, vD = (i + 3) < end;
        int offA = srcs8[i];
        int offB = srcs8[vB ? i + 1 : i];
        int offC = srcs8[vC ? i + 2 : i];
        int offD = srcs8[vD ? i + 3 : i];
        f16x8 hA = *(const f16x8*)(xlh_bytes + (size_t)(unsigned)offA + q * 16);
        f16x8 hB = *(const f16x8*)(xlh_bytes + (size_t)(unsigned)offB + q * 16);
        f16x8 hC = *(const f16x8*)(xlh_bytes + (size_t)(unsigned)offC + q * 16);
        f16x8 hD = *(const f16x8*)(xlh_bytes + (size_t)(unsigned)offD + q * 16);
        const f16x2* a2 = (const f16x2*)&hA;
        const f16x2* b2 = (const f16x2*)&hB;
        const f16x2* c2 = (const f16x2*)&hC;
        const f16x2* d2 = (const f16x2*)&hD;

        f16x2 pA2 = {(_Float16)0.f, (_Float16)0.f};
        f16x2 pB2 = pA2, pC2 = pA2, pD2 = pA2;
        #pragma unroll
        for (int j = 0; j < 4; ++j) {
            f16x2 eA = a2[j] + xr2[j];
            eA = __builtin_elementwise_max(eA, eA * slope);
            pA2 += eA * at2[j];
            f16x2 eB = b2[j] + xr2[j];
            eB = __builtin_elementwise_max(eB, eB * slope);
            pB2 += eB * at2[j];
            f16x2 eC = c2[j] + xr2[j];
            eC = __builtin_elementwise_max(eC, eC * slope);
            pC2 += eC * at2[j];
            f16x2 eD = d2[j] + xr2[j];
            eD = __builtin_elementwise_max(eD, eD * slope);
            pD2 += eD * at2[j];
        }
        float pA = (float)pA2[0] + (float)pA2[1];
        float pB = (float)pB2[0] + (float)pB2[1];
        float pC = (float)pC2[0] + (float)pC2[1];
        float pD = (float)pD2[0] + (float)pD2[1];
        pA += __shfl_xor(pA, 1); pA += __shfl_xor(pA, 2);
        pB += __shfl_xor(pB, 1); pB += __shfl_xor(pB, 2);
        pC += __shfl_xor(pC, 1); pC += __shfl_xor(pC, 2);
        pD += __shfl_xor(pD, 1); pD += __shfl_xor(pD, 2);
        float wA = __expf(pA);
        float wB = vB ? __expf(pB) : 0.f;
        float wC = vC ? __expf(pC) : 0.f;
        float wD = vD ? __expf(pD) : 0.f;
        s += (wA + wB) + (wC + wD);
        #pragma unroll
        for (int j = 0; j < 8; ++j) {
            o[j] = fmaf(wA, (float)hA[j], o[j]);
            o[j] = fmaf(wB, (float)hB[j], o[j]);
            o[j] = fmaf(wC, (float)hC[j], o[j]);
            o[j] = fmaf(wD, (float)hD[j], o[j]);
        }
    }

    float inv = 1.f / (s + 1e-16f);
    float r[8];
    #pragma unroll
    for (int j = 0; j < 8; ++j) {
        r[j] = fmaf(o[j], inv, bias[q * 8 + j]);
        if (do_relu) r[j] = fmaxf(r[j], 0.f);
    }
    if (out_half) {
        f16x8 hv;
        #pragma unroll
        for (int j = 0; j < 8; ++j) hv[j] = (_Float16)r[j];
        *(f16x8*)(outh + (size_t)node * F + q * 8) = hv;
    } else {
        float4 lo = {r[0], r[1], r[2], r[3]};
        float4 hi = {r[4], r[5], r[6], r[7]};
        *(float4*)(outf + (size_t)node * F + q * 8) = lo;
        *(float4*)(outf + (size_t)node * F + q * 8 + 4) = hi;
    }
}

// ---------------- launch ----------------

extern "C" void kernel_launch(void* const* d_in, const int* in_sizes, int n_in,
                              void* d_out, int out_size, void* d_ws, size_t ws_size,
                              hipStream_t stream)
{
    const float* x    = (const float*)d_in[0];
    const int*   ei   = (const int*)d_in[1];
    const float* Wl1  = (const float*)d_in[2];
    const float* Wr1  = (const float*)d_in[3];
    const float* Wl2  = (const float*)d_in[4];
    const float* Wr2  = (const float*)d_in[5];
    const float* bl1  = (const float*)d_in[6];
    const float* br1  = (const float*)d_in[7];
    const float* bl2  = (const float*)d_in[8];
    const float* br2  = (const float*)d_in[9];
    const float* att1 = (const float*)d_in[10];
    const float* att2 = (const float*)d_in[11];
    const float* b1   = (const float*)d_in[12];
    const float* b2   = (const float*)d_in[13];

    const int N = in_sizes[0] / F;
    const int E = in_sizes[1] / 2;
    const int* src = ei;
    const int* dst = ei + E;

    char* ws = (char*)d_ws;
    size_t off = 0;
    auto alloc = [&](size_t bytes) -> void* {
        void* p = ws + off;
        off = (off + bytes + 255) & ~(size_t)255;
        return p;
    };
    _Float16* hh   = (_Float16*)alloc((size_t)N * F * sizeof(_Float16));
    _Float16* xlh  = (_Float16*)alloc((size_t)N * F * sizeof(_Float16));
    _Float16* xrh  = (_Float16*)alloc((size_t)N * F * sizeof(_Float16));
    _Float16* Wt1l = (_Float16*)alloc((size_t)F * F * sizeof(_Float16));
    _Float16* Wt1r = (_Float16*)alloc((size_t)F * F * sizeof(_Float16));
    _Float16* Wt2l = (_Float16*)alloc((size_t)F * F * sizeof(_Float16));
    _Float16* Wt2r = (_Float16*)alloc((size_t)F * F * sizeof(_Float16));
    _Float16* attH1 = (_Float16*)alloc(F * sizeof(_Float16));
    _Float16* attH2 = (_Float16*)alloc(F * sizeof(_Float16));
    int*      row_ptr = (int*)alloc((size_t)(N + 1) * sizeof(int));
    int*      counts  = (int*)alloc((size_t)NB * G * sizeof(int));
    int*      offsets = (int*)alloc((size_t)NB * G * sizeof(int));
    unsigned* pairs   = (unsigned*)alloc((size_t)E * sizeof(unsigned));
    int*      srcs8   = (int*)alloc((size_t)E * sizeof(int));

    // bucketed CSR build + weight/att convert (4 dispatches)
    const int chunk = (E + G - 1) / G;
    hist_convw_kernel<<<G + 65, 1024, 0, stream>>>(dst, counts, E, chunk,
                                                   Wl1, Wr1, Wl2, Wr2,
                                                   Wt1l, Wt1r, Wt2l, Wt2r,
                                                   att1, att2, attH1, attH2);
    scan_fused_kernel<<<1, 1024, 0, stream>>>(counts, offsets);
    bucket_scatter_kernel<<<G, 1024, 0, stream>>>(src, dst, offsets, pairs, E, chunk);
    bucket_csr_kernel<<<NB, 256, 0, stream>>>(pairs, offsets, row_ptr, srcs8, N, E);

    const int gemm_blocks = (N + 127) / 128;
    dim3 gemm_grid(gemm_blocks, 2);
    dim3 eb(64, 4);
    const int edge_blocks = (N + 15) / 16;

    // layer 1 (A fp32, converted inline)
    mfma_gemm_kernel<1><<<gemm_grid, 512, 0, stream>>>(
        x, Wt1l, bl1, Wt1r, br1, xlh, xrh, N);
    gat_edge_kernel<<<edge_blocks, eb, 0, stream>>>(
        (const char*)xlh, xrh, srcs8, row_ptr, attH1, b1,
        nullptr, hh, N, 1, 1);

    // layer 2 (A fp16 from edge layer 1)
    mfma_gemm_kernel<0><<<gemm_grid, 512, 0, stream>>>(
        hh, Wt2l, bl2, Wt2r, br2, xlh, xrh, N);
    gat_edge_kernel<<<edge_blocks, eb, 0, stream>>>(
        (const char*)xlh, xrh, srcs8, row_ptr, attH2, b2,
        (float*)d_out, nullptr, N, 0, 0);
}